// Round 1
// baseline (5722.320 us; speedup 1.0000x reference)
//
#include <hip/hip_runtime.h>

#define N_NODES 50000
#define N_EDGES 10000
#define NNZ     800000
#define C       256
#define SLOPE   0.01f

// ---- workspace layout (bytes) ----
// e_acc : [10000][256] f32 @ 0          (10,240,000)
// n_acc : [50000][256] f32 @ 10,240,000 (51,200,000)
// Ddeg  : [50000] f32     @ 61,440,000 (200,000)
// Bdeg  : [10000] f32     @ 61,640,000 (40,000)
// g     : [256][256] f32  @ 61,680,000 (262,144)
// ---- zero region ends @ 61,942,144 ----
// e2    : [10000][256] f32 @ 61,942,144 (10,240,000)
#define OFF_EACC 0
#define OFF_NACC 10240000
#define OFF_D    61440000
#define OFF_B    61640000
#define OFF_G    61680000
#define ZERO_BYTES 61942144
#define OFF_E2   61942144

__global__ __launch_bounds__(256) void zero_kernel(float4* __restrict__ p, int n4) {
    int i = blockIdx.x * 256 + threadIdx.x;
    if (i < n4) p[i] = make_float4(0.f, 0.f, 0.f, 0.f);
}

__global__ __launch_bounds__(256) void degree_kernel(const int* __restrict__ node_idx,
                                                     const int* __restrict__ edge_idx,
                                                     float* __restrict__ Ddeg,
                                                     float* __restrict__ Bdeg) {
    int i = blockIdx.x * 256 + threadIdx.x;
    if (i < NNZ) {
        atomicAdd(&Ddeg[node_idx[i]], 1.0f);
        atomicAdd(&Bdeg[edge_idx[i]], 1.0f);
    }
}

// one wave per incidence: gather emb[node] row (64 lanes x float4), atomic-add into e_acc[edge]
__global__ __launch_bounds__(256) void scatter_edges_kernel(const float* __restrict__ emb,
                                                            const int* __restrict__ node_idx,
                                                            const int* __restrict__ edge_idx,
                                                            float* __restrict__ e_acc) {
    int inc = blockIdx.x * 4 + (threadIdx.x >> 6);
    if (inc >= NNZ) return;
    int lane = threadIdx.x & 63;
    int v = node_idx[inc];
    int e = edge_idx[inc];
    float4 val = ((const float4*)(emb + (size_t)v * C))[lane];
    float* dst = e_acc + (size_t)e * C + lane * 4;
    atomicAdd(dst + 0, val.x);
    atomicAdd(dst + 1, val.y);
    atomicAdd(dst + 2, val.z);
    atomicAdd(dst + 3, val.w);
}

// e2[m][n] = Binv[m] * sum_k e_acc[m][k] * conv_w[n][k]   (64x64 tile, 256 thr, 4x4/thread)
__global__ __launch_bounds__(256) void edge_gemm_kernel(const float* __restrict__ e_acc,
                                                        const float* __restrict__ Bdeg,
                                                        const float* __restrict__ conv_w,
                                                        float* __restrict__ e2) {
    __shared__ float As[16][65];  // [k][m]
    __shared__ float Bs[16][65];  // [k][n]
    int m0 = blockIdx.x * 64, n0 = blockIdx.y * 64;
    int tx = threadIdx.x & 15, ty = threadIdx.x >> 4;
    float acc[4][4] = {};
    for (int kb = 0; kb < C; kb += 16) {
        #pragma unroll
        for (int i = 0; i < 4; i++) {
            int idx = threadIdx.x + i * 256;   // 0..1023
            int kk = idx & 15, mm = idx >> 4;  // mm 0..63
            int m = m0 + mm;
            As[kk][mm] = (m < N_EDGES) ? e_acc[(size_t)m * C + kb + kk] : 0.0f;
            Bs[kk][mm] = conv_w[(size_t)(n0 + mm) * C + kb + kk];
        }
        __syncthreads();
        #pragma unroll
        for (int k = 0; k < 16; k++) {
            float a[4], b[4];
            #pragma unroll
            for (int r = 0; r < 4; r++) a[r] = As[k][ty * 4 + r];
            #pragma unroll
            for (int c = 0; c < 4; c++) b[c] = Bs[k][tx * 4 + c];
            #pragma unroll
            for (int r = 0; r < 4; r++)
                #pragma unroll
                for (int c = 0; c < 4; c++) acc[r][c] += a[r] * b[c];
        }
        __syncthreads();
    }
    #pragma unroll
    for (int r = 0; r < 4; r++) {
        int m = m0 + ty * 4 + r;
        if (m < N_EDGES) {
            float bd = Bdeg[m];
            float binv = (bd > 0.f) ? 1.0f / bd : 0.0f;
            #pragma unroll
            for (int c = 0; c < 4; c++)
                e2[(size_t)m * C + n0 + tx * 4 + c] = acc[r][c] * binv;
        }
    }
}

// one wave per incidence: gather e2[edge] row, atomic-add into n_acc[node]
__global__ __launch_bounds__(256) void scatter_nodes_kernel(const float* __restrict__ e2,
                                                            const int* __restrict__ node_idx,
                                                            const int* __restrict__ edge_idx,
                                                            float* __restrict__ n_acc) {
    int inc = blockIdx.x * 4 + (threadIdx.x >> 6);
    if (inc >= NNZ) return;
    int lane = threadIdx.x & 63;
    int v = node_idx[inc];
    int e = edge_idx[inc];
    float4 val = ((const float4*)(e2 + (size_t)e * C))[lane];
    float* dst = n_acc + (size_t)v * C + lane * 4;
    atomicAdd(dst + 0, val.x);
    atomicAdd(dst + 1, val.y);
    atomicAdd(dst + 2, val.z);
    atomicAdd(dst + 3, val.w);
}

// y = lrelu(n_acc * Dinv + conv_b), in place
__global__ __launch_bounds__(256) void finalize_kernel(float* __restrict__ n_acc,
                                                       const float* __restrict__ Ddeg,
                                                       const float* __restrict__ conv_b) {
    int v = blockIdx.x, c = threadIdx.x;
    float d = Ddeg[v];
    float dinv = (d > 0.f) ? 1.0f / d : 0.0f;
    float val = n_acc[(size_t)v * C + c] * dinv + conv_b[c];
    n_acc[(size_t)v * C + c] = (val > 0.f) ? val : SLOPE * val;
}

// g += partial y^T y : grid (4,4,50) output-tile x split-K, 64x64 tile per block
__global__ __launch_bounds__(256) void gram_kernel(const float* __restrict__ y,
                                                   float* __restrict__ g) {
    __shared__ float As[8][64];
    __shared__ float Bs[8][64];
    int i0 = blockIdx.x * 64, j0 = blockIdx.y * 64;
    int kbase = blockIdx.z * 1000;
    int tx = threadIdx.x & 15, ty = threadIdx.x >> 4;
    float acc[4][4] = {};
    for (int ks = 0; ks < 1000; ks += 8) {
        #pragma unroll
        for (int i = 0; i < 2; i++) {
            int idx = threadIdx.x + i * 256;  // 0..511
            int k = idx >> 6, c = idx & 63;
            const float* row = y + (size_t)(kbase + ks + k) * C;
            As[k][c] = row[i0 + c];
            Bs[k][c] = row[j0 + c];
        }
        __syncthreads();
        #pragma unroll
        for (int k = 0; k < 8; k++) {
            float a[4], b[4];
            #pragma unroll
            for (int r = 0; r < 4; r++) a[r] = As[k][ty * 4 + r];
            #pragma unroll
            for (int c = 0; c < 4; c++) b[c] = Bs[k][tx * 4 + c];
            #pragma unroll
            for (int r = 0; r < 4; r++)
                #pragma unroll
                for (int c = 0; c < 4; c++) acc[r][c] += a[r] * b[c];
        }
        __syncthreads();
    }
    #pragma unroll
    for (int r = 0; r < 4; r++)
        #pragma unroll
        for (int c = 0; c < 4; c++)
            atomicAdd(&g[(size_t)(i0 + ty * 4 + r) * C + j0 + tx * 4 + c], acc[r][c]);
}

// out[i][j] = lrelu(sum_k g[i][k]*lin_w[j][k] + lin_b[j])
__global__ __launch_bounds__(256) void out_kernel(const float* __restrict__ g,
                                                  const float* __restrict__ lin_w,
                                                  const float* __restrict__ lin_b,
                                                  float* __restrict__ out) {
    __shared__ float gs[C];
    int i = blockIdx.x, j = threadIdx.x;
    gs[j] = g[(size_t)i * C + j];
    __syncthreads();
    float acc = lin_b[j];
    const float* wrow = lin_w + (size_t)j * C;
    for (int k = 0; k < C; k++) acc += gs[k] * wrow[k];
    out[(size_t)i * C + j] = (acc > 0.f) ? acc : SLOPE * acc;
}

extern "C" void kernel_launch(void* const* d_in, const int* in_sizes, int n_in,
                              void* d_out, int out_size, void* d_ws, size_t ws_size,
                              hipStream_t stream) {
    const float* emb    = (const float*)d_in[0];
    const float* conv_w = (const float*)d_in[1];
    const float* conv_b = (const float*)d_in[2];
    const float* lin_w  = (const float*)d_in[3];
    const float* lin_b  = (const float*)d_in[4];
    const int*   eidx   = (const int*)d_in[5];
    const int* node_idx = eidx;            // edge_index[0]
    const int* edge_idx = eidx + NNZ;      // edge_index[1]

    char* ws = (char*)d_ws;
    float* e_acc = (float*)(ws + OFF_EACC);
    float* n_acc = (float*)(ws + OFF_NACC);
    float* Ddeg  = (float*)(ws + OFF_D);
    float* Bdeg  = (float*)(ws + OFF_B);
    float* g     = (float*)(ws + OFF_G);
    float* e2    = (float*)(ws + OFF_E2);
    float* out   = (float*)d_out;

    // zero accumulators (ws is poisoned 0xAA before every call)
    int n4 = ZERO_BYTES / 16;  // 3,871,384 float4s
    zero_kernel<<<(n4 + 255) / 256, 256, 0, stream>>>((float4*)ws, n4);

    degree_kernel<<<(NNZ + 255) / 256, 256, 0, stream>>>(node_idx, edge_idx, Ddeg, Bdeg);

    scatter_edges_kernel<<<NNZ / 4, 256, 0, stream>>>(emb, node_idx, edge_idx, e_acc);

    dim3 gg((N_EDGES + 63) / 64, C / 64);
    edge_gemm_kernel<<<gg, 256, 0, stream>>>(e_acc, Bdeg, conv_w, e2);

    scatter_nodes_kernel<<<NNZ / 4, 256, 0, stream>>>(e2, node_idx, edge_idx, n_acc);

    finalize_kernel<<<N_NODES, 256, 0, stream>>>(n_acc, Ddeg, conv_b);

    dim3 gr(4, 4, 50);
    gram_kernel<<<gr, 256, 0, stream>>>(n_acc, g);

    out_kernel<<<C, 256, 0, stream>>>(g, lin_w, lin_b, out);
}

// Round 2
// 715.180 us; speedup vs baseline: 8.0012x; 8.0012x over previous
//
#include <hip/hip_runtime.h>

#define N_NODES 50000
#define N_EDGES 10000
#define NNZ     800000
#define C       256
#define SLOPE   0.01f

// ---- workspace layout (bytes) ----
#define OFF_CNT_N  0          // 50000*4
#define OFF_CNT_E  200000     // 10000*4
#define OFF_CUR_N  240000     // 50000*4
#define OFF_CUR_E  440000     // 10000*4
#define OFF_G      480000     // 256*256*4
#define ZERO_BYTES 742144     // zero region [0, ZERO_BYTES)
#define OFF_RS_N   742144     // (50001)*4 (+pad)
#define OFF_RS_E   942160     // (10001)*4 (+pad)
#define OFF_BSUM_N 982176     // 256*4
#define OFF_BSUM_E 983200     // 256*4
#define OFF_CSR_E  984224     // 800000*4  (node ids grouped by edge)
#define OFF_CSR_N  4184224    // 800000*4  (edge ids grouped by node)
#define OFF_EACC   7384224    // 10000*256*4
#define OFF_E2     17624224   // 10000*256*4
#define OFF_Y      27864224   // 50000*256*2 (bf16)  -> end 53,464,224

static __device__ __forceinline__ unsigned short f2bf(float f) {
    unsigned int u = __float_as_uint(f);
    u = (u + 0x7fffu + ((u >> 16) & 1u)) >> 16;   // RNE
    return (unsigned short)u;
}
static __device__ __forceinline__ float bf2f(unsigned short h) {
    return __uint_as_float(((unsigned int)h) << 16);
}

__global__ __launch_bounds__(256) void zero_kernel(float4* __restrict__ p, int n4) {
    int i = blockIdx.x * 256 + threadIdx.x;
    if (i < n4) p[i] = make_float4(0.f, 0.f, 0.f, 0.f);
}

__global__ __launch_bounds__(256) void hist_kernel(const int* __restrict__ node_idx,
                                                   const int* __restrict__ edge_idx,
                                                   int* __restrict__ cnt_n,
                                                   int* __restrict__ cnt_e) {
    int i = blockIdx.x * 256 + threadIdx.x;
    if (i < NNZ) {
        atomicAdd(&cnt_n[node_idx[i]], 1);
        atomicAdd(&cnt_e[edge_idx[i]], 1);
    }
}

// K1: per-256-block inclusive scan; writes incl to rs[i+1], block total to bsum[b]
__global__ __launch_bounds__(256) void scan_block_kernel(const int* __restrict__ cnt, int n,
                                                         int* __restrict__ rs,
                                                         int* __restrict__ bsum) {
    __shared__ int tmp[256];
    int i = blockIdx.x * 256 + threadIdx.x;
    int v = (i < n) ? cnt[i] : 0;
    tmp[threadIdx.x] = v;
    __syncthreads();
    for (int off = 1; off < 256; off <<= 1) {
        int t = (threadIdx.x >= off) ? tmp[threadIdx.x - off] : 0;
        __syncthreads();
        tmp[threadIdx.x] += t;
        __syncthreads();
    }
    if (i < n) rs[i + 1] = tmp[threadIdx.x];
    if (threadIdx.x == 255) bsum[blockIdx.x] = tmp[255];
}

// K2: single block exclusive scan of bsum[0..nb)
__global__ __launch_bounds__(256) void scan_sums_kernel(int* __restrict__ bsum, int nb) {
    __shared__ int tmp[256];
    int v = (threadIdx.x < nb) ? bsum[threadIdx.x] : 0;
    tmp[threadIdx.x] = v;
    __syncthreads();
    for (int off = 1; off < 256; off <<= 1) {
        int t = (threadIdx.x >= off) ? tmp[threadIdx.x - off] : 0;
        __syncthreads();
        tmp[threadIdx.x] += t;
        __syncthreads();
    }
    if (threadIdx.x < nb) bsum[threadIdx.x] = tmp[threadIdx.x] - v;  // exclusive
}

// K3: rs[i+1] += bsum[i>>8]; rs[0]=0
__global__ __launch_bounds__(256) void scan_fix_kernel(int* __restrict__ rs, int n,
                                                       const int* __restrict__ bsum) {
    int i = blockIdx.x * 256 + threadIdx.x;
    if (i < n) rs[i + 1] += bsum[i >> 8];
    if (i == 0) rs[0] = 0;
}

__global__ __launch_bounds__(256) void build_csr_kernel(const int* __restrict__ node_idx,
                                                        const int* __restrict__ edge_idx,
                                                        const int* __restrict__ rs_e,
                                                        const int* __restrict__ rs_n,
                                                        int* __restrict__ cur_e,
                                                        int* __restrict__ cur_n,
                                                        int* __restrict__ csr_e,
                                                        int* __restrict__ csr_n) {
    int i = blockIdx.x * 256 + threadIdx.x;
    if (i >= NNZ) return;
    int v = node_idx[i], e = edge_idx[i];
    int pe = rs_e[e] + atomicAdd(&cur_e[e], 1);
    csr_e[pe] = v;
    int pn = rs_n[v] + atomicAdd(&cur_n[v], 1);
    csr_n[pn] = e;
}

// one wave per hyperedge: sum emb rows of incident nodes (no atomics)
__global__ __launch_bounds__(256) void edge_aggregate_kernel(const float* __restrict__ emb,
                                                             const int* __restrict__ csr_e,
                                                             const int* __restrict__ rs_e,
                                                             float* __restrict__ e_acc) {
    int e = blockIdx.x * 4 + (threadIdx.x >> 6);
    if (e >= N_EDGES) return;
    int lane = threadIdx.x & 63;
    int s = rs_e[e], t = rs_e[e + 1];
    float4 acc = make_float4(0.f, 0.f, 0.f, 0.f);
    for (int i = s; i < t; i++) {
        int v = csr_e[i];
        float4 x = ((const float4*)(emb + (size_t)v * C))[lane];
        acc.x += x.x; acc.y += x.y; acc.z += x.z; acc.w += x.w;
    }
    ((float4*)(e_acc + (size_t)e * C))[lane] = acc;
}

// e2[m][n] = Binv[m] * sum_k e_acc[m][k] * conv_w[n][k]
__global__ __launch_bounds__(256) void edge_gemm_kernel(const float* __restrict__ e_acc,
                                                        const int* __restrict__ rs_e,
                                                        const float* __restrict__ conv_w,
                                                        float* __restrict__ e2) {
    __shared__ float As[16][65];
    __shared__ float Bs[16][65];
    int m0 = blockIdx.x * 64, n0 = blockIdx.y * 64;
    int tx = threadIdx.x & 15, ty = threadIdx.x >> 4;
    float acc[4][4] = {};
    for (int kb = 0; kb < C; kb += 16) {
        #pragma unroll
        for (int i = 0; i < 4; i++) {
            int idx = threadIdx.x + i * 256;
            int kk = idx & 15, mm = idx >> 4;
            As[kk][mm] = e_acc[(size_t)(m0 + mm) * C + kb + kk];
            Bs[kk][mm] = conv_w[(size_t)(n0 + mm) * C + kb + kk];
        }
        __syncthreads();
        #pragma unroll
        for (int k = 0; k < 16; k++) {
            float a[4], b[4];
            #pragma unroll
            for (int r = 0; r < 4; r++) a[r] = As[k][ty * 4 + r];
            #pragma unroll
            for (int c = 0; c < 4; c++) b[c] = Bs[k][tx * 4 + c];
            #pragma unroll
            for (int r = 0; r < 4; r++)
                #pragma unroll
                for (int c = 0; c < 4; c++) acc[r][c] += a[r] * b[c];
        }
        __syncthreads();
    }
    #pragma unroll
    for (int r = 0; r < 4; r++) {
        int m = m0 + ty * 4 + r;
        int deg = rs_e[m + 1] - rs_e[m];
        float binv = (deg > 0) ? 1.0f / (float)deg : 0.0f;
        #pragma unroll
        for (int c = 0; c < 4; c++)
            e2[(size_t)m * C + n0 + tx * 4 + c] = acc[r][c] * binv;
    }
}

// one wave per node: sum e2 rows, fused Dinv+bias+leakyReLU, store bf16
__global__ __launch_bounds__(256) void node_aggregate_kernel(const float* __restrict__ e2,
                                                             const int* __restrict__ csr_n,
                                                             const int* __restrict__ rs_n,
                                                             const float* __restrict__ conv_b,
                                                             unsigned short* __restrict__ y) {
    int v = blockIdx.x * 4 + (threadIdx.x >> 6);
    if (v >= N_NODES) return;
    int lane = threadIdx.x & 63;
    int s = rs_n[v], t = rs_n[v + 1];
    float4 acc = make_float4(0.f, 0.f, 0.f, 0.f);
    for (int i = s; i < t; i++) {
        int e = csr_n[i];
        float4 x = ((const float4*)(e2 + (size_t)e * C))[lane];
        acc.x += x.x; acc.y += x.y; acc.z += x.z; acc.w += x.w;
    }
    float dinv = (t > s) ? 1.0f / (float)(t - s) : 0.0f;
    float4 b = ((const float4*)conv_b)[lane];
    float r0 = acc.x * dinv + b.x;
    float r1 = acc.y * dinv + b.y;
    float r2 = acc.z * dinv + b.z;
    float r3 = acc.w * dinv + b.w;
    r0 = (r0 > 0.f) ? r0 : SLOPE * r0;
    r1 = (r1 > 0.f) ? r1 : SLOPE * r1;
    r2 = (r2 > 0.f) ? r2 : SLOPE * r2;
    r3 = (r3 > 0.f) ? r3 : SLOPE * r3;
    ushort4 o;
    o.x = f2bf(r0); o.y = f2bf(r1); o.z = f2bf(r2); o.w = f2bf(r3);
    ((ushort4*)(y + (size_t)v * C))[lane] = o;
}

// g += partial y^T y : grid (4,4,50), 64x64 tile, bf16 in / fp32 math
__global__ __launch_bounds__(256) void gram_kernel(const unsigned short* __restrict__ y,
                                                   float* __restrict__ g) {
    __shared__ float As[8][64];
    __shared__ float Bs[8][64];
    int i0 = blockIdx.x * 64, j0 = blockIdx.y * 64;
    int kbase = blockIdx.z * 1000;
    int tx = threadIdx.x & 15, ty = threadIdx.x >> 4;
    float acc[4][4] = {};
    for (int ks = 0; ks < 1000; ks += 8) {
        #pragma unroll
        for (int i = 0; i < 2; i++) {
            int idx = threadIdx.x + i * 256;  // 0..511
            int k = idx >> 6, c = idx & 63;
            const unsigned short* row = y + (size_t)(kbase + ks + k) * C;
            As[k][c] = bf2f(row[i0 + c]);
            Bs[k][c] = bf2f(row[j0 + c]);
        }
        __syncthreads();
        #pragma unroll
        for (int k = 0; k < 8; k++) {
            float a[4], b[4];
            #pragma unroll
            for (int r = 0; r < 4; r++) a[r] = As[k][ty * 4 + r];
            #pragma unroll
            for (int c = 0; c < 4; c++) b[c] = Bs[k][tx * 4 + c];
            #pragma unroll
            for (int r = 0; r < 4; r++)
                #pragma unroll
                for (int c = 0; c < 4; c++) acc[r][c] += a[r] * b[c];
        }
        __syncthreads();
    }
    #pragma unroll
    for (int r = 0; r < 4; r++)
        #pragma unroll
        for (int c = 0; c < 4; c++)
            atomicAdd(&g[(size_t)(i0 + ty * 4 + r) * C + j0 + tx * 4 + c], acc[r][c]);
}

__global__ __launch_bounds__(256) void out_kernel(const float* __restrict__ g,
                                                  const float* __restrict__ lin_w,
                                                  const float* __restrict__ lin_b,
                                                  float* __restrict__ out) {
    __shared__ float gs[C];
    int i = blockIdx.x, j = threadIdx.x;
    gs[j] = g[(size_t)i * C + j];
    __syncthreads();
    float acc = lin_b[j];
    const float* wrow = lin_w + (size_t)j * C;
    for (int k = 0; k < C; k++) acc += gs[k] * wrow[k];
    out[(size_t)i * C + j] = (acc > 0.f) ? acc : SLOPE * acc;
}

extern "C" void kernel_launch(void* const* d_in, const int* in_sizes, int n_in,
                              void* d_out, int out_size, void* d_ws, size_t ws_size,
                              hipStream_t stream) {
    const float* emb    = (const float*)d_in[0];
    const float* conv_w = (const float*)d_in[1];
    const float* conv_b = (const float*)d_in[2];
    const float* lin_w  = (const float*)d_in[3];
    const float* lin_b  = (const float*)d_in[4];
    const int*   eidx   = (const int*)d_in[5];
    const int* node_idx = eidx;        // edge_index[0]
    const int* edge_idx = eidx + NNZ;  // edge_index[1]

    char* ws = (char*)d_ws;
    int* cnt_n = (int*)(ws + OFF_CNT_N);
    int* cnt_e = (int*)(ws + OFF_CNT_E);
    int* cur_n = (int*)(ws + OFF_CUR_N);
    int* cur_e = (int*)(ws + OFF_CUR_E);
    float* g   = (float*)(ws + OFF_G);
    int* rs_n  = (int*)(ws + OFF_RS_N);
    int* rs_e  = (int*)(ws + OFF_RS_E);
    int* bsum_n = (int*)(ws + OFF_BSUM_N);
    int* bsum_e = (int*)(ws + OFF_BSUM_E);
    int* csr_e = (int*)(ws + OFF_CSR_E);
    int* csr_n = (int*)(ws + OFF_CSR_N);
    float* e_acc = (float*)(ws + OFF_EACC);
    float* e2    = (float*)(ws + OFF_E2);
    unsigned short* y = (unsigned short*)(ws + OFF_Y);
    float* out = (float*)d_out;

    // zero counters + cursors + g
    int n4 = ZERO_BYTES / 16;
    zero_kernel<<<(n4 + 255) / 256, 256, 0, stream>>>((float4*)ws, n4);

    hist_kernel<<<(NNZ + 255) / 256, 256, 0, stream>>>(node_idx, edge_idx, cnt_n, cnt_e);

    // scan node counts -> rs_n (196 blocks), edge counts -> rs_e (40 blocks)
    scan_block_kernel<<<(N_NODES + 255) / 256, 256, 0, stream>>>(cnt_n, N_NODES, rs_n, bsum_n);
    scan_block_kernel<<<(N_EDGES + 255) / 256, 256, 0, stream>>>(cnt_e, N_EDGES, rs_e, bsum_e);
    scan_sums_kernel<<<1, 256, 0, stream>>>(bsum_n, (N_NODES + 255) / 256);
    scan_sums_kernel<<<1, 256, 0, stream>>>(bsum_e, (N_EDGES + 255) / 256);
    scan_fix_kernel<<<(N_NODES + 255) / 256, 256, 0, stream>>>(rs_n, N_NODES, bsum_n);
    scan_fix_kernel<<<(N_EDGES + 255) / 256, 256, 0, stream>>>(rs_e, N_EDGES, bsum_e);

    build_csr_kernel<<<(NNZ + 255) / 256, 256, 0, stream>>>(node_idx, edge_idx, rs_e, rs_n,
                                                            cur_e, cur_n, csr_e, csr_n);

    edge_aggregate_kernel<<<(N_EDGES + 3) / 4, 256, 0, stream>>>(emb, csr_e, rs_e, e_acc);

    dim3 gg(N_EDGES / 64 + 1, C / 64);
    edge_gemm_kernel<<<dim3((N_EDGES + 63) / 64, C / 64), 256, 0, stream>>>(e_acc, rs_e, conv_w, e2);

    node_aggregate_kernel<<<(N_NODES + 3) / 4, 256, 0, stream>>>(e2, csr_n, rs_n, conv_b, y);

    dim3 gr(4, 4, 50);
    gram_kernel<<<gr, 256, 0, stream>>>(y, g);

    out_kernel<<<C, 256, 0, stream>>>(g, lin_w, lin_b, out);
}

// Round 3
// 569.946 us; speedup vs baseline: 10.0401x; 1.2548x over previous
//
#include <hip/hip_runtime.h>

#define N_NODES 50000
#define N_EDGES 10000
#define NNZ     800000
#define C       256
#define SLOPE   0.01f
#define KTOT    50048   // node count padded to multiple of 64
#define KCHUNK  1088    // 17 * 64
#define NZB     46      // KTOT / KCHUNK

// ---- workspace layout (bytes) ----
#define OFF_CNT_N  0          // 50000*4
#define OFF_CNT_E  200000     // 10000*4
#define OFF_CUR_N  240000     // 50000*4
#define OFF_CUR_E  440000     // 10000*4
#define OFF_G      480000     // 256*256*4
#define ZERO_BYTES 742144
#define OFF_RS_N   742144     // 50001*4 (+pad)
#define OFF_RS_E   942160     // 10001*4 (+pad)
#define OFF_BSUM_N 982176
#define OFF_BSUM_E 983200
#define OFF_CSR_E  984224     // 800000*4 (node ids grouped by edge)
#define OFF_CSR_N  4184224    // 800000*4 (edge ids grouped by node)
#define OFF_EMBH   7384224    // 50000*256*2 bf16 (dead after edge_aggregate)
#define OFF_YT     7384224    // 256*50048*2 bf16 — ALIASES embh (+24KB of e_acc head);
                              // written by node_aggregate AFTER embh/e_acc are dead
#define OFF_EACC   32984224   // 10000*256*4 f32 (dead after edge_gemm)
#define OFF_E2     43224224   // 10000*256*2 bf16
// end: 48,344,224 bytes

typedef __attribute__((ext_vector_type(8))) short short8;
typedef __attribute__((ext_vector_type(4))) float floatx4;

static __device__ __forceinline__ unsigned short f2bf(float f) {
    unsigned int u = __float_as_uint(f);
    u = (u + 0x7fffu + ((u >> 16) & 1u)) >> 16;   // RNE
    return (unsigned short)u;
}

// unpack uint4 (8 bf16) and accumulate into a[0..7]
static __device__ __forceinline__ void acc_bf8(const uint4 d, float* a) {
    a[0] += __uint_as_float(d.x << 16);
    a[1] += __uint_as_float(d.x & 0xffff0000u);
    a[2] += __uint_as_float(d.y << 16);
    a[3] += __uint_as_float(d.y & 0xffff0000u);
    a[4] += __uint_as_float(d.z << 16);
    a[5] += __uint_as_float(d.z & 0xffff0000u);
    a[6] += __uint_as_float(d.w << 16);
    a[7] += __uint_as_float(d.w & 0xffff0000u);
}

__global__ __launch_bounds__(256) void zero_kernel(float4* __restrict__ p, int n4) {
    int i = blockIdx.x * 256 + threadIdx.x;
    if (i < n4) p[i] = make_float4(0.f, 0.f, 0.f, 0.f);
}

// emb f32 -> bf16 (8 elems/thread)
__global__ __launch_bounds__(256) void cast_emb_kernel(const float4* __restrict__ emb4,
                                                       uint4* __restrict__ embh4) {
    int i = blockIdx.x * 256 + threadIdx.x;   // 1.6M threads
    float4 f0 = emb4[2 * i], f1 = emb4[2 * i + 1];
    uint4 o;
    o.x = f2bf(f0.x) | ((unsigned)f2bf(f0.y) << 16);
    o.y = f2bf(f0.z) | ((unsigned)f2bf(f0.w) << 16);
    o.z = f2bf(f1.x) | ((unsigned)f2bf(f1.y) << 16);
    o.w = f2bf(f1.z) | ((unsigned)f2bf(f1.w) << 16);
    embh4[i] = o;
}

__global__ __launch_bounds__(256) void hist_kernel(const int* __restrict__ node_idx,
                                                   const int* __restrict__ edge_idx,
                                                   int* __restrict__ cnt_n,
                                                   int* __restrict__ cnt_e) {
    int i = blockIdx.x * 256 + threadIdx.x;
    if (i < NNZ) {
        atomicAdd(&cnt_n[node_idx[i]], 1);
        atomicAdd(&cnt_e[edge_idx[i]], 1);
    }
}

__global__ __launch_bounds__(256) void scan_block_kernel(const int* __restrict__ cnt, int n,
                                                         int* __restrict__ rs,
                                                         int* __restrict__ bsum) {
    __shared__ int tmp[256];
    int i = blockIdx.x * 256 + threadIdx.x;
    int v = (i < n) ? cnt[i] : 0;
    tmp[threadIdx.x] = v;
    __syncthreads();
    for (int off = 1; off < 256; off <<= 1) {
        int t = (threadIdx.x >= off) ? tmp[threadIdx.x - off] : 0;
        __syncthreads();
        tmp[threadIdx.x] += t;
        __syncthreads();
    }
    if (i < n) rs[i + 1] = tmp[threadIdx.x];
    if (threadIdx.x == 255) bsum[blockIdx.x] = tmp[255];
}

__global__ __launch_bounds__(256) void scan_sums_kernel(int* __restrict__ bsum, int nb) {
    __shared__ int tmp[256];
    int v = (threadIdx.x < nb) ? bsum[threadIdx.x] : 0;
    tmp[threadIdx.x] = v;
    __syncthreads();
    for (int off = 1; off < 256; off <<= 1) {
        int t = (threadIdx.x >= off) ? tmp[threadIdx.x - off] : 0;
        __syncthreads();
        tmp[threadIdx.x] += t;
        __syncthreads();
    }
    if (threadIdx.x < nb) bsum[threadIdx.x] = tmp[threadIdx.x] - v;  // exclusive
}

__global__ __launch_bounds__(256) void scan_fix_kernel(int* __restrict__ rs, int n,
                                                       const int* __restrict__ bsum) {
    int i = blockIdx.x * 256 + threadIdx.x;
    if (i < n) rs[i + 1] += bsum[i >> 8];
    if (i == 0) rs[0] = 0;
}

__global__ __launch_bounds__(256) void build_csr_kernel(const int* __restrict__ node_idx,
                                                        const int* __restrict__ edge_idx,
                                                        const int* __restrict__ rs_e,
                                                        const int* __restrict__ rs_n,
                                                        int* __restrict__ cur_e,
                                                        int* __restrict__ cur_n,
                                                        int* __restrict__ csr_e,
                                                        int* __restrict__ csr_n) {
    int i = blockIdx.x * 256 + threadIdx.x;
    if (i >= NNZ) return;
    int v = node_idx[i], e = edge_idx[i];
    int pe = rs_e[e] + atomicAdd(&cur_e[e], 1);
    csr_e[pe] = v;
    int pn = rs_n[v] + atomicAdd(&cur_n[v], 1);
    csr_n[pn] = e;
}

// one wave per hyperedge; half-wave reads a full 256-ch bf16 row (32 lanes x 16B)
__global__ __launch_bounds__(256) void edge_aggregate_kernel(const uint4* __restrict__ embh4,
                                                             const int* __restrict__ csr_e,
                                                             const int* __restrict__ rs_e,
                                                             float* __restrict__ e_acc) {
    int e = blockIdx.x * 4 + (threadIdx.x >> 6);
    if (e >= N_EDGES) return;
    int lane = threadIdx.x & 63;
    int half = lane >> 5, l32 = lane & 31;
    int s = rs_e[e], t = rs_e[e + 1];
    float a[8] = {0.f, 0.f, 0.f, 0.f, 0.f, 0.f, 0.f, 0.f};
    for (int i = s + half; i < t; i += 2) {
        int v = csr_e[i];
        uint4 d = embh4[(size_t)v * 32 + l32];
        acc_bf8(d, a);
    }
    #pragma unroll
    for (int j = 0; j < 8; j++) a[j] += __shfl_xor(a[j], 32);
    if (half == 0) {
        float* dst = e_acc + (size_t)e * C + l32 * 8;
        ((float4*)dst)[0] = make_float4(a[0], a[1], a[2], a[3]);
        ((float4*)dst)[1] = make_float4(a[4], a[5], a[6], a[7]);
    }
}

// e2[m][n] = Binv[m] * sum_k e_acc[m][k] * conv_w[n][k], bf16 out
__global__ __launch_bounds__(256) void edge_gemm_kernel(const float* __restrict__ e_acc,
                                                        const int* __restrict__ rs_e,
                                                        const float* __restrict__ conv_w,
                                                        unsigned short* __restrict__ e2h) {
    __shared__ float As[16][65];
    __shared__ float Bs[16][65];
    int m0 = blockIdx.x * 64, n0 = blockIdx.y * 64;
    int tx = threadIdx.x & 15, ty = threadIdx.x >> 4;
    float acc[4][4] = {};
    for (int kb = 0; kb < C; kb += 16) {
        #pragma unroll
        for (int i = 0; i < 4; i++) {
            int idx = threadIdx.x + i * 256;
            int kk = idx & 15, mm = idx >> 4;
            int m = m0 + mm;
            As[kk][mm] = (m < N_EDGES) ? e_acc[(size_t)m * C + kb + kk] : 0.0f;
            Bs[kk][mm] = conv_w[(size_t)(n0 + mm) * C + kb + kk];
        }
        __syncthreads();
        #pragma unroll
        for (int k = 0; k < 16; k++) {
            float a[4], b[4];
            #pragma unroll
            for (int r = 0; r < 4; r++) a[r] = As[k][ty * 4 + r];
            #pragma unroll
            for (int c = 0; c < 4; c++) b[c] = Bs[k][tx * 4 + c];
            #pragma unroll
            for (int r = 0; r < 4; r++)
                #pragma unroll
                for (int c = 0; c < 4; c++) acc[r][c] += a[r] * b[c];
        }
        __syncthreads();
    }
    #pragma unroll
    for (int r = 0; r < 4; r++) {
        int m = m0 + ty * 4 + r;
        if (m < N_EDGES) {
            int deg = rs_e[m + 1] - rs_e[m];
            float binv = (deg > 0) ? 1.0f / (float)deg : 0.0f;
            ushort4 o;
            o.x = f2bf(acc[r][0] * binv);
            o.y = f2bf(acc[r][1] * binv);
            o.z = f2bf(acc[r][2] * binv);
            o.w = f2bf(acc[r][3] * binv);
            *(ushort4*)(e2h + (size_t)m * C + n0 + tx * 4) = o;
        }
    }
}

// 64 nodes per block; aggregate + fused Dinv/bias/lrelu, write yT (transposed via LDS)
__global__ __launch_bounds__(256) void node_aggregate_t_kernel(const uint4* __restrict__ e2h4,
                                                               const int* __restrict__ csr_n,
                                                               const int* __restrict__ rs_n,
                                                               const float* __restrict__ conv_b,
                                                               unsigned short* __restrict__ yT) {
    __shared__ __align__(16) unsigned short T[64][256];  // [node][ch]
    int n0 = blockIdx.x * 64;
    int tid = threadIdx.x;
    int w = tid >> 6, lane = tid & 63;
    int half = lane >> 5, l32 = lane & 31;
    float4 b0 = ((const float4*)conv_b)[l32 * 2];
    float4 b1 = ((const float4*)conv_b)[l32 * 2 + 1];
    float bb[8] = {b0.x, b0.y, b0.z, b0.w, b1.x, b1.y, b1.z, b1.w};
    for (int q = 0; q < 16; q++) {
        int v = n0 + w * 16 + q;                 // wave-uniform
        float a[8] = {0.f, 0.f, 0.f, 0.f, 0.f, 0.f, 0.f, 0.f};
        int s = 0, t = 0;
        if (v < N_NODES) {
            s = rs_n[v]; t = rs_n[v + 1];
            for (int i = s + half; i < t; i += 2) {
                int e = csr_n[i];
                uint4 d = e2h4[(size_t)e * 32 + l32];
                acc_bf8(d, a);
            }
        }
        #pragma unroll
        for (int j = 0; j < 8; j++) a[j] += __shfl_xor(a[j], 32);
        float dinv = (t > s) ? 1.0f / (float)(t - s) : 0.0f;
        unsigned int pk[4];
        #pragma unroll
        for (int j = 0; j < 4; j++) {
            float r0 = a[2 * j] * dinv + bb[2 * j];
            float r1 = a[2 * j + 1] * dinv + bb[2 * j + 1];
            r0 = (r0 > 0.f) ? r0 : SLOPE * r0;
            r1 = (r1 > 0.f) ? r1 : SLOPE * r1;
            if (v >= N_NODES) { r0 = 0.f; r1 = 0.f; }   // zero-pad rows
            pk[j] = f2bf(r0) | ((unsigned)f2bf(r1) << 16);
        }
        if (half == 0) {
            uint4 o; o.x = pk[0]; o.y = pk[1]; o.z = pk[2]; o.w = pk[3];
            *(uint4*)(&T[w * 16 + q][l32 * 8]) = o;
        }
    }
    __syncthreads();
    // write out transposed: thread = channel, 64 nodes in 8-short chunks
    int ch = tid;
    #pragma unroll
    for (int jj = 0; jj < 8; jj++) {
        uint4 o;
        o.x = T[jj * 8 + 0][ch] | ((unsigned)T[jj * 8 + 1][ch] << 16);
        o.y = T[jj * 8 + 2][ch] | ((unsigned)T[jj * 8 + 3][ch] << 16);
        o.z = T[jj * 8 + 4][ch] | ((unsigned)T[jj * 8 + 5][ch] << 16);
        o.w = T[jj * 8 + 6][ch] | ((unsigned)T[jj * 8 + 7][ch] << 16);
        *(uint4*)(yT + (size_t)ch * KTOT + n0 + jj * 8) = o;
    }
}

// g += yT-tile^T yT-tile via mfma_f32_16x16x32_bf16; grid (4,4,NZB)
__global__ __launch_bounds__(256) void gram_mfma_kernel(const unsigned short* __restrict__ yT,
                                                        float* __restrict__ g) {
    __shared__ __align__(16) unsigned short As[64 * 72];  // [col][k], stride 72
    __shared__ __align__(16) unsigned short Bs[64 * 72];
    int i0 = blockIdx.x * 64, j0 = blockIdx.y * 64;
    int kb0 = blockIdx.z * KCHUNK;
    int tid = threadIdx.x;
    int w = tid >> 6, lane = tid & 63;
    int col = lane & 15, quad = lane >> 4;
    floatx4 acc[4] = {};
    for (int step = 0; step < 17; step++) {
        int kb = kb0 + step * 64;
        __syncthreads();
        #pragma unroll
        for (int l = 0; l < 2; l++) {
            int slot = tid + l * 256;          // 0..511
            int row = slot >> 3, grp = slot & 7;
            uint4 da = *(const uint4*)(yT + (size_t)(i0 + row) * KTOT + kb + grp * 8);
            *(uint4*)(&As[row * 72 + grp * 8]) = da;
            uint4 db = *(const uint4*)(yT + (size_t)(j0 + row) * KTOT + kb + grp * 8);
            *(uint4*)(&Bs[row * 72 + grp * 8]) = db;
        }
        __syncthreads();
        #pragma unroll
        for (int sub = 0; sub < 2; sub++) {
            short8 a = *(const short8*)(&As[(w * 16 + col) * 72 + sub * 32 + quad * 8]);
            #pragma unroll
            for (int jt = 0; jt < 4; jt++) {
                short8 b = *(const short8*)(&Bs[(jt * 16 + col) * 72 + sub * 32 + quad * 8]);
                acc[jt] = __builtin_amdgcn_mfma_f32_16x16x32_bf16(a, b, acc[jt], 0, 0, 0);
            }
        }
    }
    #pragma unroll
    for (int jt = 0; jt < 4; jt++)
        #pragma unroll
        for (int r = 0; r < 4; r++)
            atomicAdd(&g[(size_t)(i0 + w * 16 + quad * 4 + r) * C + j0 + jt * 16 + col],
                      acc[jt][r]);
}

__global__ __launch_bounds__(256) void out_kernel(const float* __restrict__ g,
                                                  const float* __restrict__ lin_w,
                                                  const float* __restrict__ lin_b,
                                                  float* __restrict__ out) {
    __shared__ float gs[C];
    int i = blockIdx.x, j = threadIdx.x;
    gs[j] = g[(size_t)i * C + j];
    __syncthreads();
    float acc = lin_b[j];
    const float* wrow = lin_w + (size_t)j * C;
    for (int k = 0; k < C; k++) acc += gs[k] * wrow[k];
    out[(size_t)i * C + j] = (acc > 0.f) ? acc : SLOPE * acc;
}

extern "C" void kernel_launch(void* const* d_in, const int* in_sizes, int n_in,
                              void* d_out, int out_size, void* d_ws, size_t ws_size,
                              hipStream_t stream) {
    const float* emb    = (const float*)d_in[0];
    const float* conv_w = (const float*)d_in[1];
    const float* conv_b = (const float*)d_in[2];
    const float* lin_w  = (const float*)d_in[3];
    const float* lin_b  = (const float*)d_in[4];
    const int*   eidx   = (const int*)d_in[5];
    const int* node_idx = eidx;        // edge_index[0]
    const int* edge_idx = eidx + NNZ;  // edge_index[1]

    char* ws = (char*)d_ws;
    int* cnt_n = (int*)(ws + OFF_CNT_N);
    int* cnt_e = (int*)(ws + OFF_CNT_E);
    int* cur_n = (int*)(ws + OFF_CUR_N);
    int* cur_e = (int*)(ws + OFF_CUR_E);
    float* g   = (float*)(ws + OFF_G);
    int* rs_n  = (int*)(ws + OFF_RS_N);
    int* rs_e  = (int*)(ws + OFF_RS_E);
    int* bsum_n = (int*)(ws + OFF_BSUM_N);
    int* bsum_e = (int*)(ws + OFF_BSUM_E);
    int* csr_e = (int*)(ws + OFF_CSR_E);
    int* csr_n = (int*)(ws + OFF_CSR_N);
    uint4* embh4 = (uint4*)(ws + OFF_EMBH);
    float* e_acc = (float*)(ws + OFF_EACC);
    unsigned short* e2h = (unsigned short*)(ws + OFF_E2);
    unsigned short* yT  = (unsigned short*)(ws + OFF_YT);
    float* out = (float*)d_out;

    int n4 = ZERO_BYTES / 16;
    zero_kernel<<<(n4 + 255) / 256, 256, 0, stream>>>((float4*)ws, n4);

    cast_emb_kernel<<<6250, 256, 0, stream>>>((const float4*)emb, embh4);

    hist_kernel<<<(NNZ + 255) / 256, 256, 0, stream>>>(node_idx, edge_idx, cnt_n, cnt_e);

    scan_block_kernel<<<(N_NODES + 255) / 256, 256, 0, stream>>>(cnt_n, N_NODES, rs_n, bsum_n);
    scan_block_kernel<<<(N_EDGES + 255) / 256, 256, 0, stream>>>(cnt_e, N_EDGES, rs_e, bsum_e);
    scan_sums_kernel<<<1, 256, 0, stream>>>(bsum_n, (N_NODES + 255) / 256);
    scan_sums_kernel<<<1, 256, 0, stream>>>(bsum_e, (N_EDGES + 255) / 256);
    scan_fix_kernel<<<(N_NODES + 255) / 256, 256, 0, stream>>>(rs_n, N_NODES, bsum_n);
    scan_fix_kernel<<<(N_EDGES + 255) / 256, 256, 0, stream>>>(rs_e, N_EDGES, bsum_e);

    build_csr_kernel<<<(NNZ + 255) / 256, 256, 0, stream>>>(node_idx, edge_idx, rs_e, rs_n,
                                                            cur_e, cur_n, csr_e, csr_n);

    edge_aggregate_kernel<<<(N_EDGES + 3) / 4, 256, 0, stream>>>(embh4, csr_e, rs_e, e_acc);

    edge_gemm_kernel<<<dim3((N_EDGES + 63) / 64, C / 64), 256, 0, stream>>>(e_acc, rs_e, conv_w, e2h);

    node_aggregate_t_kernel<<<KTOT / 64, 256, 0, stream>>>((const uint4*)e2h, csr_n, rs_n,
                                                           conv_b, yT);

    gram_mfma_kernel<<<dim3(4, 4, NZB), 256, 0, stream>>>(yT, g);

    out_kernel<<<C, 256, 0, stream>>>(g, lin_w, lin_b, out);
}

// Round 4
// 487.815 us; speedup vs baseline: 11.7305x; 1.1684x over previous
//
#include <hip/hip_runtime.h>

#define N_NODES 50000
#define N_EDGES 10000
#define NNZ     800000
#define C       256
#define SLOPE   0.01f
#define KTOT    50048   // node count padded to multiple of 64
#define KCHUNK  1088    // 17 * 64
#define NZB     46      // KTOT / KCHUNK

#define NB      250     // coarse buckets per side
#define EB_E    40      // edges per bucket   (250*40  = 10000)
#define EB_N    200     // nodes per bucket   (250*200 = 50000)
#define CHUNK   3125    // NNZ / 256 blocks
#define CAP     6000    // LDS item capacity in bucket_sort (mean 3200, sd ~57)

// ---- workspace layout (bytes) ----
#define OFF_CNT_N   0          // 50000*4
#define OFF_CNT_E   200000     // 10000*4
#define OFF_CBKT_E  240000     // 250*4 (+pad)
#define OFF_CBKT_N  241024     // 250*4 (+pad)
#define OFF_G       242048     // 256*256*4
#define ZERO_BYTES  504192     // zero region [0, ZERO_BYTES), /16 ok
#define OFF_RS_N    504192     // 50001*4 (+pad)
#define OFF_RS_E    704208     // 10001*4 (+pad)
#define OFF_BSUM_N  744224     // 256*4
#define OFF_BSUM_E  745248     // 256*4
#define OFF_BUF_E   746272     // 800000*4 bucketed items (edge side)
#define OFF_BUF_N   3946272    // 800000*4 bucketed items (node side)
#define OFF_CSR_E   7146272    // 800000*4 node ids grouped by edge
#define OFF_CSR_N   10346272   // 800000*4 edge ids grouped by node
#define OFF_EMBH    13546272   // 50000*256*2 bf16 (dead after edge_aggregate)
#define OFF_YT      13546272   // 256*50048*2 bf16 — ALIASES embh (embh dead first)
#define OFF_EACC    39170848   // 10000*256*4 f32
#define OFF_E2      49410848   // 10000*256*2 bf16 -> end 54,530,848

typedef __attribute__((ext_vector_type(8))) short short8;
typedef __attribute__((ext_vector_type(4))) float floatx4;

static __device__ __forceinline__ unsigned short f2bf(float f) {
    unsigned int u = __float_as_uint(f);
    u = (u + 0x7fffu + ((u >> 16) & 1u)) >> 16;   // RNE
    return (unsigned short)u;
}

// unpack uint4 (8 bf16) and accumulate into a[0..7]
static __device__ __forceinline__ void acc_bf8(const uint4 d, float* a) {
    a[0] += __uint_as_float(d.x << 16);
    a[1] += __uint_as_float(d.x & 0xffff0000u);
    a[2] += __uint_as_float(d.y << 16);
    a[3] += __uint_as_float(d.y & 0xffff0000u);
    a[4] += __uint_as_float(d.z << 16);
    a[5] += __uint_as_float(d.z & 0xffff0000u);
    a[6] += __uint_as_float(d.w << 16);
    a[7] += __uint_as_float(d.w & 0xffff0000u);
}

__global__ __launch_bounds__(256) void zero_kernel(float4* __restrict__ p, int n4) {
    int i = blockIdx.x * 256 + threadIdx.x;
    if (i < n4) p[i] = make_float4(0.f, 0.f, 0.f, 0.f);
}

// emb f32 -> bf16 (8 elems/thread)
__global__ __launch_bounds__(256) void cast_emb_kernel(const float4* __restrict__ emb4,
                                                       uint4* __restrict__ embh4) {
    int i = blockIdx.x * 256 + threadIdx.x;   // 1.6M threads
    float4 f0 = emb4[2 * i], f1 = emb4[2 * i + 1];
    uint4 o;
    o.x = f2bf(f0.x) | ((unsigned)f2bf(f0.y) << 16);
    o.y = f2bf(f0.z) | ((unsigned)f2bf(f0.w) << 16);
    o.z = f2bf(f1.x) | ((unsigned)f2bf(f1.y) << 16);
    o.w = f2bf(f1.z) | ((unsigned)f2bf(f1.w) << 16);
    embh4[i] = o;
}

__global__ __launch_bounds__(256) void hist_kernel(const int* __restrict__ node_idx,
                                                   const int* __restrict__ edge_idx,
                                                   int* __restrict__ cnt_n,
                                                   int* __restrict__ cnt_e) {
    int i = blockIdx.x * 256 + threadIdx.x;
    if (i < NNZ) {
        atomicAdd(&cnt_n[node_idx[i]], 1);
        atomicAdd(&cnt_e[edge_idx[i]], 1);
    }
}

__global__ __launch_bounds__(256) void scan_block_kernel(const int* __restrict__ cnt, int n,
                                                         int* __restrict__ rs,
                                                         int* __restrict__ bsum) {
    __shared__ int tmp[256];
    int i = blockIdx.x * 256 + threadIdx.x;
    int v = (i < n) ? cnt[i] : 0;
    tmp[threadIdx.x] = v;
    __syncthreads();
    for (int off = 1; off < 256; off <<= 1) {
        int t = (threadIdx.x >= off) ? tmp[threadIdx.x - off] : 0;
        __syncthreads();
        tmp[threadIdx.x] += t;
        __syncthreads();
    }
    if (i < n) rs[i + 1] = tmp[threadIdx.x];
    if (threadIdx.x == 255) bsum[blockIdx.x] = tmp[255];
}

__global__ __launch_bounds__(256) void scan_sums_kernel(int* __restrict__ bsum, int nb) {
    __shared__ int tmp[256];
    int v = (threadIdx.x < nb) ? bsum[threadIdx.x] : 0;
    tmp[threadIdx.x] = v;
    __syncthreads();
    for (int off = 1; off < 256; off <<= 1) {
        int t = (threadIdx.x >= off) ? tmp[threadIdx.x - off] : 0;
        __syncthreads();
        tmp[threadIdx.x] += t;
        __syncthreads();
    }
    if (threadIdx.x < nb) bsum[threadIdx.x] = tmp[threadIdx.x] - v;  // exclusive
}

__global__ __launch_bounds__(256) void scan_fix_kernel(int* __restrict__ rs, int n,
                                                       const int* __restrict__ bsum) {
    int i = blockIdx.x * 256 + threadIdx.x;
    if (i < n) rs[i + 1] += bsum[i >> 8];
    if (i == 0) rs[0] = 0;
}

// pass 1: scatter incidences into coarse buckets (both sides), line-dense writes
__global__ __launch_bounds__(256) void bucket_scatter_kernel(const int* __restrict__ node_idx,
                                                             const int* __restrict__ edge_idx,
                                                             const int* __restrict__ rs_e,
                                                             const int* __restrict__ rs_n,
                                                             int* __restrict__ cur_e,
                                                             int* __restrict__ cur_n,
                                                             int* __restrict__ buf_e,
                                                             int* __restrict__ buf_n) {
    __shared__ int he[NB], hn[NB], be[NB], bn[NB];
    int tid = threadIdx.x;
    int base = blockIdx.x * CHUNK;
    for (int i = tid; i < NB; i += 256) { he[i] = 0; hn[i] = 0; }
    __syncthreads();
    for (int i = tid; i < CHUNK; i += 256) {
        int e = edge_idx[base + i], v = node_idx[base + i];
        atomicAdd(&he[e / EB_E], 1);
        atomicAdd(&hn[v / EB_N], 1);
    }
    __syncthreads();
    for (int k = tid; k < NB; k += 256) {
        int c = he[k];
        be[k] = rs_e[k * EB_E] + (c ? atomicAdd(&cur_e[k], c) : 0);
        int cn = hn[k];
        bn[k] = rs_n[k * EB_N] + (cn ? atomicAdd(&cur_n[k], cn) : 0);
    }
    __syncthreads();
    for (int i = tid; i < NB; i += 256) { he[i] = 0; hn[i] = 0; }
    __syncthreads();
    for (int i = tid; i < CHUNK; i += 256) {
        int e = edge_idx[base + i], v = node_idx[base + i];
        int ke = e / EB_E, kn = v / EB_N;
        int oe = atomicAdd(&he[ke], 1);
        buf_e[be[ke] + oe] = (v << 6) | (e - ke * EB_E);
        int on = atomicAdd(&hn[kn], 1);
        buf_n[bn[kn] + on] = (e << 8) | (v - kn * EB_N);
    }
}

// pass 2: per-bucket LDS counting sort -> final CSR (contiguous coalesced output)
// blocks [0,NB): edge side;  [NB,2*NB): node side
__global__ __launch_bounds__(256) void bucket_sort_kernel(const int* __restrict__ buf_e,
                                                          const int* __restrict__ buf_n,
                                                          const int* __restrict__ rs_e,
                                                          const int* __restrict__ rs_n,
                                                          int* __restrict__ csr_e,
                                                          int* __restrict__ csr_n) {
    __shared__ int A[CAP];
    __shared__ int h[EB_N], bs[EB_N];
    int tid = threadIdx.x;
    bool edgeSide = blockIdx.x < NB;
    int k = edgeSide ? blockIdx.x : blockIdx.x - NB;
    int eb = edgeSide ? EB_E : EB_N;
    int shift = edgeSide ? 6 : 8;
    int mask = (1 << shift) - 1;
    const int* rs  = edgeSide ? rs_e : rs_n;
    const int* buf = edgeSide ? buf_e : buf_n;
    int* csr       = edgeSide ? csr_e : csr_n;
    int base = rs[k * eb];
    int cnt = rs[k * eb + eb] - base;
    for (int i = tid; i < eb; i += 256) h[i] = 0;
    __syncthreads();
    for (int i = tid; i < cnt; i += 256) {
        int it = buf[base + i];
        if (i < CAP) A[i] = it;
        atomicAdd(&h[it & mask], 1);
    }
    __syncthreads();
    if (tid == 0) {
        int s = 0;
        for (int j = 0; j < eb; j++) { bs[j] = s; s += h[j]; }
    }
    __syncthreads();
    for (int i = tid; i < eb; i += 256) h[i] = 0;
    __syncthreads();
    for (int i = tid; i < cnt; i += 256) {
        int it = (i < CAP) ? A[i] : buf[base + i];
        int loc = it & mask;
        int off = bs[loc] + atomicAdd(&h[loc], 1);
        csr[base + off] = it >> shift;
    }
}

// one wave per hyperedge; half-wave reads a full 256-ch bf16 row (32 lanes x 16B)
__global__ __launch_bounds__(256) void edge_aggregate_kernel(const uint4* __restrict__ embh4,
                                                             const int* __restrict__ csr_e,
                                                             const int* __restrict__ rs_e,
                                                             float* __restrict__ e_acc) {
    int e = blockIdx.x * 4 + (threadIdx.x >> 6);
    if (e >= N_EDGES) return;
    int lane = threadIdx.x & 63;
    int half = lane >> 5, l32 = lane & 31;
    int s = rs_e[e], t = rs_e[e + 1];
    float a[8] = {0.f, 0.f, 0.f, 0.f, 0.f, 0.f, 0.f, 0.f};
    for (int i = s + half; i < t; i += 2) {
        int v = csr_e[i];
        uint4 d = embh4[(size_t)v * 32 + l32];
        acc_bf8(d, a);
    }
    #pragma unroll
    for (int j = 0; j < 8; j++) a[j] += __shfl_xor(a[j], 32);
    if (half == 0) {
        float* dst = e_acc + (size_t)e * C + l32 * 8;
        ((float4*)dst)[0] = make_float4(a[0], a[1], a[2], a[3]);
        ((float4*)dst)[1] = make_float4(a[4], a[5], a[6], a[7]);
    }
}

// e2[m][n] = Binv[m] * sum_k e_acc[m][k] * conv_w[n][k], bf16 out
__global__ __launch_bounds__(256) void edge_gemm_kernel(const float* __restrict__ e_acc,
                                                        const int* __restrict__ rs_e,
                                                        const float* __restrict__ conv_w,
                                                        unsigned short* __restrict__ e2h) {
    __shared__ float As[16][65];
    __shared__ float Bs[16][65];
    int m0 = blockIdx.x * 64, n0 = blockIdx.y * 64;
    int tx = threadIdx.x & 15, ty = threadIdx.x >> 4;
    float acc[4][4] = {};
    for (int kb = 0; kb < C; kb += 16) {
        #pragma unroll
        for (int i = 0; i < 4; i++) {
            int idx = threadIdx.x + i * 256;
            int kk = idx & 15, mm = idx >> 4;
            int m = m0 + mm;
            As[kk][mm] = (m < N_EDGES) ? e_acc[(size_t)m * C + kb + kk] : 0.0f;
            Bs[kk][mm] = conv_w[(size_t)(n0 + mm) * C + kb + kk];
        }
        __syncthreads();
        #pragma unroll
        for (int k = 0; k < 16; k++) {
            float a[4], b[4];
            #pragma unroll
            for (int r = 0; r < 4; r++) a[r] = As[k][ty * 4 + r];
            #pragma unroll
            for (int c = 0; c < 4; c++) b[c] = Bs[k][tx * 4 + c];
            #pragma unroll
            for (int r = 0; r < 4; r++)
                #pragma unroll
                for (int c = 0; c < 4; c++) acc[r][c] += a[r] * b[c];
        }
        __syncthreads();
    }
    #pragma unroll
    for (int r = 0; r < 4; r++) {
        int m = m0 + ty * 4 + r;
        if (m < N_EDGES) {
            int deg = rs_e[m + 1] - rs_e[m];
            float binv = (deg > 0) ? 1.0f / (float)deg : 0.0f;
            ushort4 o;
            o.x = f2bf(acc[r][0] * binv);
            o.y = f2bf(acc[r][1] * binv);
            o.z = f2bf(acc[r][2] * binv);
            o.w = f2bf(acc[r][3] * binv);
            *(ushort4*)(e2h + (size_t)m * C + n0 + tx * 4) = o;
        }
    }
}

// 64 nodes per block; aggregate + fused Dinv/bias/lrelu, write yT (transposed via LDS)
__global__ __launch_bounds__(256) void node_aggregate_t_kernel(const uint4* __restrict__ e2h4,
                                                               const int* __restrict__ csr_n,
                                                               const int* __restrict__ rs_n,
                                                               const float* __restrict__ conv_b,
                                                               unsigned short* __restrict__ yT) {
    __shared__ __align__(16) unsigned short T[64][256];  // [node][ch]
    int n0 = blockIdx.x * 64;
    int tid = threadIdx.x;
    int w = tid >> 6, lane = tid & 63;
    int half = lane >> 5, l32 = lane & 31;
    float4 b0 = ((const float4*)conv_b)[l32 * 2];
    float4 b1 = ((const float4*)conv_b)[l32 * 2 + 1];
    float bb[8] = {b0.x, b0.y, b0.z, b0.w, b1.x, b1.y, b1.z, b1.w};
    for (int q = 0; q < 16; q++) {
        int v = n0 + w * 16 + q;                 // wave-uniform
        float a[8] = {0.f, 0.f, 0.f, 0.f, 0.f, 0.f, 0.f, 0.f};
        int s = 0, t = 0;
        if (v < N_NODES) {
            s = rs_n[v]; t = rs_n[v + 1];
            for (int i = s + half; i < t; i += 2) {
                int e = csr_n[i];
                uint4 d = e2h4[(size_t)e * 32 + l32];
                acc_bf8(d, a);
            }
        }
        #pragma unroll
        for (int j = 0; j < 8; j++) a[j] += __shfl_xor(a[j], 32);
        float dinv = (t > s) ? 1.0f / (float)(t - s) : 0.0f;
        unsigned int pk[4];
        #pragma unroll
        for (int j = 0; j < 4; j++) {
            float r0 = a[2 * j] * dinv + bb[2 * j];
            float r1 = a[2 * j + 1] * dinv + bb[2 * j + 1];
            r0 = (r0 > 0.f) ? r0 : SLOPE * r0;
            r1 = (r1 > 0.f) ? r1 : SLOPE * r1;
            if (v >= N_NODES) { r0 = 0.f; r1 = 0.f; }   // zero-pad rows
            pk[j] = f2bf(r0) | ((unsigned)f2bf(r1) << 16);
        }
        if (half == 0) {
            uint4 o; o.x = pk[0]; o.y = pk[1]; o.z = pk[2]; o.w = pk[3];
            *(uint4*)(&T[w * 16 + q][l32 * 8]) = o;
        }
    }
    __syncthreads();
    int ch = tid;
    #pragma unroll
    for (int jj = 0; jj < 8; jj++) {
        uint4 o;
        o.x = T[jj * 8 + 0][ch] | ((unsigned)T[jj * 8 + 1][ch] << 16);
        o.y = T[jj * 8 + 2][ch] | ((unsigned)T[jj * 8 + 3][ch] << 16);
        o.z = T[jj * 8 + 4][ch] | ((unsigned)T[jj * 8 + 5][ch] << 16);
        o.w = T[jj * 8 + 6][ch] | ((unsigned)T[jj * 8 + 7][ch] << 16);
        *(uint4*)(yT + (size_t)ch * KTOT + n0 + jj * 8) = o;
    }
}

// g += yT-tile^T yT-tile via mfma_f32_16x16x32_bf16; grid (4,4,NZB)
__global__ __launch_bounds__(256) void gram_mfma_kernel(const unsigned short* __restrict__ yT,
                                                        float* __restrict__ g) {
    __shared__ __align__(16) unsigned short As[64 * 72];  // [col][k], stride 72
    __shared__ __align__(16) unsigned short Bs[64 * 72];
    int i0 = blockIdx.x * 64, j0 = blockIdx.y * 64;
    int kb0 = blockIdx.z * KCHUNK;
    int tid = threadIdx.x;
    int w = tid >> 6, lane = tid & 63;
    int col = lane & 15, quad = lane >> 4;
    floatx4 acc[4] = {};
    for (int step = 0; step < 17; step++) {
        int kb = kb0 + step * 64;
        __syncthreads();
        #pragma unroll
        for (int l = 0; l < 2; l++) {
            int slot = tid + l * 256;          // 0..511
            int row = slot >> 3, grp = slot & 7;
            uint4 da = *(const uint4*)(yT + (size_t)(i0 + row) * KTOT + kb + grp * 8);
            *(uint4*)(&As[row * 72 + grp * 8]) = da;
            uint4 db = *(const uint4*)(yT + (size_t)(j0 + row) * KTOT + kb + grp * 8);
            *(uint4*)(&Bs[row * 72 + grp * 8]) = db;
        }
        __syncthreads();
        #pragma unroll
        for (int sub = 0; sub < 2; sub++) {
            short8 a = *(const short8*)(&As[(w * 16 + col) * 72 + sub * 32 + quad * 8]);
            #pragma unroll
            for (int jt = 0; jt < 4; jt++) {
                short8 b = *(const short8*)(&Bs[(jt * 16 + col) * 72 + sub * 32 + quad * 8]);
                acc[jt] = __builtin_amdgcn_mfma_f32_16x16x32_bf16(a, b, acc[jt], 0, 0, 0);
            }
        }
    }
    #pragma unroll
    for (int jt = 0; jt < 4; jt++)
        #pragma unroll
        for (int r = 0; r < 4; r++)
            atomicAdd(&g[(size_t)(i0 + w * 16 + quad * 4 + r) * C + j0 + jt * 16 + col],
                      acc[jt][r]);
}

__global__ __launch_bounds__(256) void out_kernel(const float* __restrict__ g,
                                                  const float* __restrict__ lin_w,
                                                  const float* __restrict__ lin_b,
                                                  float* __restrict__ out) {
    __shared__ float gs[C];
    int i = blockIdx.x, j = threadIdx.x;
    gs[j] = g[(size_t)i * C + j];
    __syncthreads();
    float acc = lin_b[j];
    const float* wrow = lin_w + (size_t)j * C;
    for (int k = 0; k < C; k++) acc += gs[k] * wrow[k];
    out[(size_t)i * C + j] = (acc > 0.f) ? acc : SLOPE * acc;
}

extern "C" void kernel_launch(void* const* d_in, const int* in_sizes, int n_in,
                              void* d_out, int out_size, void* d_ws, size_t ws_size,
                              hipStream_t stream) {
    const float* emb    = (const float*)d_in[0];
    const float* conv_w = (const float*)d_in[1];
    const float* conv_b = (const float*)d_in[2];
    const float* lin_w  = (const float*)d_in[3];
    const float* lin_b  = (const float*)d_in[4];
    const int*   eidx   = (const int*)d_in[5];
    const int* node_idx = eidx;        // edge_index[0]
    const int* edge_idx = eidx + NNZ;  // edge_index[1]

    char* ws = (char*)d_ws;
    int* cnt_n = (int*)(ws + OFF_CNT_N);
    int* cnt_e = (int*)(ws + OFF_CNT_E);
    int* cur_e = (int*)(ws + OFF_CBKT_E);
    int* cur_n = (int*)(ws + OFF_CBKT_N);
    float* g   = (float*)(ws + OFF_G);
    int* rs_n  = (int*)(ws + OFF_RS_N);
    int* rs_e  = (int*)(ws + OFF_RS_E);
    int* bsum_n = (int*)(ws + OFF_BSUM_N);
    int* bsum_e = (int*)(ws + OFF_BSUM_E);
    int* buf_e = (int*)(ws + OFF_BUF_E);
    int* buf_n = (int*)(ws + OFF_BUF_N);
    int* csr_e = (int*)(ws + OFF_CSR_E);
    int* csr_n = (int*)(ws + OFF_CSR_N);
    uint4* embh4 = (uint4*)(ws + OFF_EMBH);
    float* e_acc = (float*)(ws + OFF_EACC);
    unsigned short* e2h = (unsigned short*)(ws + OFF_E2);
    unsigned short* yT  = (unsigned short*)(ws + OFF_YT);
    float* out = (float*)d_out;

    int n4 = ZERO_BYTES / 16;
    zero_kernel<<<(n4 + 255) / 256, 256, 0, stream>>>((float4*)ws, n4);

    cast_emb_kernel<<<6250, 256, 0, stream>>>((const float4*)emb, embh4);

    hist_kernel<<<(NNZ + 255) / 256, 256, 0, stream>>>(node_idx, edge_idx, cnt_n, cnt_e);

    scan_block_kernel<<<(N_NODES + 255) / 256, 256, 0, stream>>>(cnt_n, N_NODES, rs_n, bsum_n);
    scan_block_kernel<<<(N_EDGES + 255) / 256, 256, 0, stream>>>(cnt_e, N_EDGES, rs_e, bsum_e);
    scan_sums_kernel<<<1, 256, 0, stream>>>(bsum_n, (N_NODES + 255) / 256);
    scan_sums_kernel<<<1, 256, 0, stream>>>(bsum_e, (N_EDGES + 255) / 256);
    scan_fix_kernel<<<(N_NODES + 255) / 256, 256, 0, stream>>>(rs_n, N_NODES, bsum_n);
    scan_fix_kernel<<<(N_EDGES + 255) / 256, 256, 0, stream>>>(rs_e, N_EDGES, bsum_e);

    bucket_scatter_kernel<<<256, 256, 0, stream>>>(node_idx, edge_idx, rs_e, rs_n,
                                                   cur_e, cur_n, buf_e, buf_n);

    bucket_sort_kernel<<<2 * NB, 256, 0, stream>>>(buf_e, buf_n, rs_e, rs_n, csr_e, csr_n);

    edge_aggregate_kernel<<<(N_EDGES + 3) / 4, 256, 0, stream>>>(embh4, csr_e, rs_e, e_acc);

    edge_gemm_kernel<<<dim3((N_EDGES + 63) / 64, C / 64), 256, 0, stream>>>(e_acc, rs_e, conv_w, e2h);

    node_aggregate_t_kernel<<<KTOT / 64, 256, 0, stream>>>((const uint4*)e2h, csr_n, rs_n,
                                                           conv_b, yT);

    gram_mfma_kernel<<<dim3(4, 4, NZB), 256, 0, stream>>>(yT, g);

    out_kernel<<<C, 256, 0, stream>>>(g, lin_w, lin_b, out);
}

// Round 6
// 421.633 us; speedup vs baseline: 13.5718x; 1.1570x over previous
//
#include <hip/hip_runtime.h>

#define N_NODES 50000
#define N_EDGES 10000
#define NNZ     800000
#define C       256
#define SLOPE   0.01f
#define KTOT    50048   // node count padded to multiple of 64
#define KCHUNK  1088    // 17 * 64
#define NZB     46      // KTOT / KCHUNK

#define NB      250     // coarse buckets per side
#define EB_E    40      // edges per bucket   (250*40  = 10000)
#define EB_N    200     // nodes per bucket   (250*200 = 50000)
#define CHUNK   3125    // NNZ / 256 blocks
#define CAP     6000    // LDS item capacity in bucket_sort (mean 3200, sd ~57)

// ---- workspace layout (bytes) ----
#define OFF_CNT_N   0          // 50000*4
#define OFF_CNT_E   200000     // 10000*4
#define OFF_CBKT_E  240000     // 250*4 (+pad)
#define OFF_CBKT_N  241024     // 250*4 (+pad)
#define OFF_G       242048     // 256*256*4
#define ZERO_BYTES  504192     // zero region [0, ZERO_BYTES), /16 ok
#define OFF_RS_N    504192     // 50001*4 (+pad)
#define OFF_RS_E    704208     // 10001*4 (+pad)
#define OFF_BSUM_N  744224     // 256*4
#define OFF_BSUM_E  745248     // 256*4
#define OFF_BUF_E   746272     // 800000*4 bucketed items (edge side)
#define OFF_BUF_N   3946272    // 800000*4 bucketed items (node side)
#define OFF_CSR_E   7146272    // 800000*4 node ids grouped by edge
#define OFF_CSR_N   10346272   // 800000*4 edge ids grouped by node
#define OFF_EMBH    13546272   // 50000*256*2 bf16 (dead after edge_aggregate)
#define OFF_YT      13546272   // 256*50048*2 bf16 — ALIASES embh (embh dead first)
#define OFF_EACC    39170848   // 10000*256*4 f32
#define OFF_E2      49410848   // 10000*256*2 bf16 -> end 54,530,848

typedef __attribute__((ext_vector_type(8))) short short8;
typedef __attribute__((ext_vector_type(4))) float floatx4;

static __device__ __forceinline__ unsigned short f2bf(float f) {
    unsigned int u = __float_as_uint(f);
    u = (u + 0x7fffu + ((u >> 16) & 1u)) >> 16;   // RNE
    return (unsigned short)u;
}

// unpack uint4 (8 bf16) and accumulate into a[0..7]
static __device__ __forceinline__ void acc_bf8(const uint4 d, float* a) {
    a[0] += __uint_as_float(d.x << 16);
    a[1] += __uint_as_float(d.x & 0xffff0000u);
    a[2] += __uint_as_float(d.y << 16);
    a[3] += __uint_as_float(d.y & 0xffff0000u);
    a[4] += __uint_as_float(d.z << 16);
    a[5] += __uint_as_float(d.z & 0xffff0000u);
    a[6] += __uint_as_float(d.w << 16);
    a[7] += __uint_as_float(d.w & 0xffff0000u);
}

// this half-wave accumulates rows csr[s+half], csr[s+half+2], ... < t.
// Index loads are same-address broadcast loads (NO cross-lane ops — safe under
// divergence, unlike __shfl whose inactive source lanes return undefined).
// 4 independent index->row chains in flight.
static __device__ __forceinline__ void gather_rows(const uint4* __restrict__ tbl4,
                                                   const int* __restrict__ csr,
                                                   int s, int t, int half, int l32,
                                                   float* a) {
    int i = s + half;
    for (; i + 6 < t; i += 8) {
        int e0 = csr[i];
        int e1 = csr[i + 2];
        int e2 = csr[i + 4];
        int e3 = csr[i + 6];
        uint4 d0 = tbl4[(size_t)e0 * 32 + l32];
        uint4 d1 = tbl4[(size_t)e1 * 32 + l32];
        uint4 d2 = tbl4[(size_t)e2 * 32 + l32];
        uint4 d3 = tbl4[(size_t)e3 * 32 + l32];
        acc_bf8(d0, a); acc_bf8(d1, a); acc_bf8(d2, a); acc_bf8(d3, a);
    }
    for (; i < t; i += 2) {
        uint4 d = tbl4[(size_t)csr[i] * 32 + l32];
        acc_bf8(d, a);
    }
}

__global__ __launch_bounds__(256) void zero_kernel(float4* __restrict__ p, int n4) {
    int i = blockIdx.x * 256 + threadIdx.x;
    if (i < n4) p[i] = make_float4(0.f, 0.f, 0.f, 0.f);
}

// emb f32 -> bf16 (8 elems/thread)
__global__ __launch_bounds__(256) void cast_emb_kernel(const float4* __restrict__ emb4,
                                                       uint4* __restrict__ embh4) {
    int i = blockIdx.x * 256 + threadIdx.x;   // 1.6M threads
    float4 f0 = emb4[2 * i], f1 = emb4[2 * i + 1];
    uint4 o;
    o.x = f2bf(f0.x) | ((unsigned)f2bf(f0.y) << 16);
    o.y = f2bf(f0.z) | ((unsigned)f2bf(f0.w) << 16);
    o.z = f2bf(f1.x) | ((unsigned)f2bf(f1.y) << 16);
    o.w = f2bf(f1.z) | ((unsigned)f2bf(f1.w) << 16);
    embh4[i] = o;
}

__global__ __launch_bounds__(256) void hist_kernel(const int* __restrict__ node_idx,
                                                   const int* __restrict__ edge_idx,
                                                   int* __restrict__ cnt_n,
                                                   int* __restrict__ cnt_e) {
    int i = blockIdx.x * 256 + threadIdx.x;
    if (i < NNZ) {
        atomicAdd(&cnt_n[node_idx[i]], 1);
        atomicAdd(&cnt_e[edge_idx[i]], 1);
    }
}

__global__ __launch_bounds__(256) void scan_block_kernel(const int* __restrict__ cnt, int n,
                                                         int* __restrict__ rs,
                                                         int* __restrict__ bsum) {
    __shared__ int tmp[256];
    int i = blockIdx.x * 256 + threadIdx.x;
    int v = (i < n) ? cnt[i] : 0;
    tmp[threadIdx.x] = v;
    __syncthreads();
    for (int off = 1; off < 256; off <<= 1) {
        int t = (threadIdx.x >= off) ? tmp[threadIdx.x - off] : 0;
        __syncthreads();
        tmp[threadIdx.x] += t;
        __syncthreads();
    }
    if (i < n) rs[i + 1] = tmp[threadIdx.x];
    if (threadIdx.x == 255) bsum[blockIdx.x] = tmp[255];
}

__global__ __launch_bounds__(256) void scan_sums_kernel(int* __restrict__ bsum, int nb) {
    __shared__ int tmp[256];
    int v = (threadIdx.x < nb) ? bsum[threadIdx.x] : 0;
    tmp[threadIdx.x] = v;
    __syncthreads();
    for (int off = 1; off < 256; off <<= 1) {
        int t = (threadIdx.x >= off) ? tmp[threadIdx.x - off] : 0;
        __syncthreads();
        tmp[threadIdx.x] += t;
        __syncthreads();
    }
    if (threadIdx.x < nb) bsum[threadIdx.x] = tmp[threadIdx.x] - v;  // exclusive
}

__global__ __launch_bounds__(256) void scan_fix_kernel(int* __restrict__ rs, int n,
                                                       const int* __restrict__ bsum) {
    int i = blockIdx.x * 256 + threadIdx.x;
    if (i < n) rs[i + 1] += bsum[i >> 8];
    if (i == 0) rs[0] = 0;
}

// pass 1: scatter incidences into coarse buckets (both sides), line-dense writes
__global__ __launch_bounds__(256) void bucket_scatter_kernel(const int* __restrict__ node_idx,
                                                             const int* __restrict__ edge_idx,
                                                             const int* __restrict__ rs_e,
                                                             const int* __restrict__ rs_n,
                                                             int* __restrict__ cur_e,
                                                             int* __restrict__ cur_n,
                                                             int* __restrict__ buf_e,
                                                             int* __restrict__ buf_n) {
    __shared__ int he[NB], hn[NB], be[NB], bn[NB];
    int tid = threadIdx.x;
    int base = blockIdx.x * CHUNK;
    for (int i = tid; i < NB; i += 256) { he[i] = 0; hn[i] = 0; }
    __syncthreads();
    for (int i = tid; i < CHUNK; i += 256) {
        int e = edge_idx[base + i], v = node_idx[base + i];
        atomicAdd(&he[e / EB_E], 1);
        atomicAdd(&hn[v / EB_N], 1);
    }
    __syncthreads();
    for (int k = tid; k < NB; k += 256) {
        int c = he[k];
        be[k] = rs_e[k * EB_E] + (c ? atomicAdd(&cur_e[k], c) : 0);
        int cn = hn[k];
        bn[k] = rs_n[k * EB_N] + (cn ? atomicAdd(&cur_n[k], cn) : 0);
    }
    __syncthreads();
    for (int i = tid; i < NB; i += 256) { he[i] = 0; hn[i] = 0; }
    __syncthreads();
    for (int i = tid; i < CHUNK; i += 256) {
        int e = edge_idx[base + i], v = node_idx[base + i];
        int ke = e / EB_E, kn = v / EB_N;
        int oe = atomicAdd(&he[ke], 1);
        buf_e[be[ke] + oe] = (v << 6) | (e - ke * EB_E);
        int on = atomicAdd(&hn[kn], 1);
        buf_n[bn[kn] + on] = (e << 8) | (v - kn * EB_N);
    }
}

// pass 2: per-bucket LDS counting sort -> final CSR (contiguous coalesced output)
__global__ __launch_bounds__(256) void bucket_sort_kernel(const int* __restrict__ buf_e,
                                                          const int* __restrict__ buf_n,
                                                          const int* __restrict__ rs_e,
                                                          const int* __restrict__ rs_n,
                                                          int* __restrict__ csr_e,
                                                          int* __restrict__ csr_n) {
    __shared__ int A[CAP];
    __shared__ int h[EB_N], bs[EB_N];
    int tid = threadIdx.x;
    bool edgeSide = blockIdx.x < NB;
    int k = edgeSide ? blockIdx.x : blockIdx.x - NB;
    int eb = edgeSide ? EB_E : EB_N;
    int shift = edgeSide ? 6 : 8;
    int mask = (1 << shift) - 1;
    const int* rs  = edgeSide ? rs_e : rs_n;
    const int* buf = edgeSide ? buf_e : buf_n;
    int* csr       = edgeSide ? csr_e : csr_n;
    int base = rs[k * eb];
    int cnt = rs[k * eb + eb] - base;
    for (int i = tid; i < eb; i += 256) h[i] = 0;
    __syncthreads();
    for (int i = tid; i < cnt; i += 256) {
        int it = buf[base + i];
        if (i < CAP) A[i] = it;
        atomicAdd(&h[it & mask], 1);
    }
    __syncthreads();
    if (tid == 0) {
        int s = 0;
        for (int j = 0; j < eb; j++) { bs[j] = s; s += h[j]; }
    }
    __syncthreads();
    for (int i = tid; i < eb; i += 256) h[i] = 0;
    __syncthreads();
    for (int i = tid; i < cnt; i += 256) {
        int it = (i < CAP) ? A[i] : buf[base + i];
        int loc = it & mask;
        int off = bs[loc] + atomicAdd(&h[loc], 1);
        csr[base + off] = it >> shift;
    }
}

// one wave per hyperedge; 4-deep pipelined gathers (broadcast index loads)
__global__ __launch_bounds__(256) void edge_aggregate_kernel(const uint4* __restrict__ embh4,
                                                             const int* __restrict__ csr_e,
                                                             const int* __restrict__ rs_e,
                                                             float* __restrict__ e_acc) {
    int e = blockIdx.x * 4 + (threadIdx.x >> 6);
    if (e >= N_EDGES) return;
    int lane = threadIdx.x & 63;
    int half = lane >> 5, l32 = lane & 31;
    int s = rs_e[e], t = rs_e[e + 1];
    float a[8] = {0.f, 0.f, 0.f, 0.f, 0.f, 0.f, 0.f, 0.f};
    gather_rows(embh4, csr_e, s, t, half, l32, a);
    #pragma unroll
    for (int j = 0; j < 8; j++) a[j] += __shfl_xor(a[j], 32);
    if (half == 0) {
        float* dst = e_acc + (size_t)e * C + l32 * 8;
        ((float4*)dst)[0] = make_float4(a[0], a[1], a[2], a[3]);
        ((float4*)dst)[1] = make_float4(a[4], a[5], a[6], a[7]);
    }
}

// e2[m][n] = Binv[m] * sum_k e_acc[m][k] * conv_w[n][k], bf16 out
__global__ __launch_bounds__(256) void edge_gemm_kernel(const float* __restrict__ e_acc,
                                                        const int* __restrict__ rs_e,
                                                        const float* __restrict__ conv_w,
                                                        unsigned short* __restrict__ e2h) {
    __shared__ float As[16][65];
    __shared__ float Bs[16][65];
    int m0 = blockIdx.x * 64, n0 = blockIdx.y * 64;
    int tx = threadIdx.x & 15, ty = threadIdx.x >> 4;
    float acc[4][4] = {};
    for (int kb = 0; kb < C; kb += 16) {
        #pragma unroll
        for (int i = 0; i < 4; i++) {
            int idx = threadIdx.x + i * 256;
            int kk = idx & 15, mm = idx >> 4;
            int m = m0 + mm;
            As[kk][mm] = (m < N_EDGES) ? e_acc[(size_t)m * C + kb + kk] : 0.0f;
            Bs[kk][mm] = conv_w[(size_t)(n0 + mm) * C + kb + kk];
        }
        __syncthreads();
        #pragma unroll
        for (int k = 0; k < 16; k++) {
            float a[4], b[4];
            #pragma unroll
            for (int r = 0; r < 4; r++) a[r] = As[k][ty * 4 + r];
            #pragma unroll
            for (int c = 0; c < 4; c++) b[c] = Bs[k][tx * 4 + c];
            #pragma unroll
            for (int r = 0; r < 4; r++)
                #pragma unroll
                for (int c = 0; c < 4; c++) acc[r][c] += a[r] * b[c];
        }
        __syncthreads();
    }
    #pragma unroll
    for (int r = 0; r < 4; r++) {
        int m = m0 + ty * 4 + r;
        if (m < N_EDGES) {
            int deg = rs_e[m + 1] - rs_e[m];
            float binv = (deg > 0) ? 1.0f / (float)deg : 0.0f;
            ushort4 o;
            o.x = f2bf(acc[r][0] * binv);
            o.y = f2bf(acc[r][1] * binv);
            o.z = f2bf(acc[r][2] * binv);
            o.w = f2bf(acc[r][3] * binv);
            *(ushort4*)(e2h + (size_t)m * C + n0 + tx * 4) = o;
        }
    }
}

// 32 nodes per block (4 waves x 8 nodes); pipelined gathers; fused
// Dinv/bias/lrelu; write yT (transposed via LDS)
__global__ __launch_bounds__(256) void node_aggregate_t_kernel(const uint4* __restrict__ e2h4,
                                                               const int* __restrict__ csr_n,
                                                               const int* __restrict__ rs_n,
                                                               const float* __restrict__ conv_b,
                                                               unsigned short* __restrict__ yT) {
    __shared__ __align__(16) unsigned short T[32][256];  // [node][ch]
    int n0 = blockIdx.x * 32;
    int tid = threadIdx.x;
    int w = tid >> 6, lane = tid & 63;
    int half = lane >> 5, l32 = lane & 31;
    int base = n0 + w * 8;
    // prefetch rs for this wave's 8 nodes; __shfl below runs with ALL 64 lanes
    // active (uniform q loop) so inactive-source-lane hazard does not apply
    int rsv = rs_n[min(base + lane, N_NODES)];
    float4 b0 = ((const float4*)conv_b)[l32 * 2];
    float4 b1 = ((const float4*)conv_b)[l32 * 2 + 1];
    float bb[8] = {b0.x, b0.y, b0.z, b0.w, b1.x, b1.y, b1.z, b1.w};
    for (int q = 0; q < 8; q++) {
        int v = base + q;
        int s = __shfl(rsv, q), t = __shfl(rsv, q + 1);
        float a[8] = {0.f, 0.f, 0.f, 0.f, 0.f, 0.f, 0.f, 0.f};
        gather_rows(e2h4, csr_n, s, t, half, l32, a);
        #pragma unroll
        for (int j = 0; j < 8; j++) a[j] += __shfl_xor(a[j], 32);
        float dinv = (t > s) ? 1.0f / (float)(t - s) : 0.0f;
        unsigned int pk[4];
        #pragma unroll
        for (int j = 0; j < 4; j++) {
            float r0 = a[2 * j] * dinv + bb[2 * j];
            float r1 = a[2 * j + 1] * dinv + bb[2 * j + 1];
            r0 = (r0 > 0.f) ? r0 : SLOPE * r0;
            r1 = (r1 > 0.f) ? r1 : SLOPE * r1;
            if (v >= N_NODES) { r0 = 0.f; r1 = 0.f; }   // zero-pad rows
            pk[j] = f2bf(r0) | ((unsigned)f2bf(r1) << 16);
        }
        if (half == 0) {
            uint4 o; o.x = pk[0]; o.y = pk[1]; o.z = pk[2]; o.w = pk[3];
            *(uint4*)(&T[w * 8 + q][l32 * 8]) = o;
        }
    }
    __syncthreads();
    int ch = tid;
    #pragma unroll
    for (int jj = 0; jj < 4; jj++) {
        uint4 o;
        o.x = T[jj * 8 + 0][ch] | ((unsigned)T[jj * 8 + 1][ch] << 16);
        o.y = T[jj * 8 + 2][ch] | ((unsigned)T[jj * 8 + 3][ch] << 16);
        o.z = T[jj * 8 + 4][ch] | ((unsigned)T[jj * 8 + 5][ch] << 16);
        o.w = T[jj * 8 + 6][ch] | ((unsigned)T[jj * 8 + 7][ch] << 16);
        *(uint4*)(yT + (size_t)ch * KTOT + n0 + jj * 8) = o;
    }
}

// g += yT-tile^T yT-tile via mfma_f32_16x16x32_bf16; grid (4,4,NZB)
__global__ __launch_bounds__(256) void gram_mfma_kernel(const unsigned short* __restrict__ yT,
                                                        float* __restrict__ g) {
    __shared__ __align__(16) unsigned short As[64 * 72];  // [col][k], stride 72
    __shared__ __align__(16) unsigned short Bs[64 * 72];
    int i0 = blockIdx.x * 64, j0 = blockIdx.y * 64;
    int kb0 = blockIdx.z * KCHUNK;
    int tid = threadIdx.x;
    int w = tid >> 6, lane = tid & 63;
    int col = lane & 15, quad = lane >> 4;
    floatx4 acc[4] = {};
    for (int step = 0; step < 17; step++) {
        int kb = kb0 + step * 64;
        __syncthreads();
        #pragma unroll
        for (int l = 0; l < 2; l++) {
            int slot = tid + l * 256;          // 0..511
            int row = slot >> 3, grp = slot & 7;
            uint4 da = *(const uint4*)(yT + (size_t)(i0 + row) * KTOT + kb + grp * 8);
            *(uint4*)(&As[row * 72 + grp * 8]) = da;
            uint4 db = *(const uint4*)(yT + (size_t)(j0 + row) * KTOT + kb + grp * 8);
            *(uint4*)(&Bs[row * 72 + grp * 8]) = db;
        }
        __syncthreads();
        #pragma unroll
        for (int sub = 0; sub < 2; sub++) {
            short8 a = *(const short8*)(&As[(w * 16 + col) * 72 + sub * 32 + quad * 8]);
            #pragma unroll
            for (int jt = 0; jt < 4; jt++) {
                short8 b = *(const short8*)(&Bs[(jt * 16 + col) * 72 + sub * 32 + quad * 8]);
                acc[jt] = __builtin_amdgcn_mfma_f32_16x16x32_bf16(a, b, acc[jt], 0, 0, 0);
            }
        }
    }
    #pragma unroll
    for (int jt = 0; jt < 4; jt++)
        #pragma unroll
        for (int r = 0; r < 4; r++)
            atomicAdd(&g[(size_t)(i0 + w * 16 + quad * 4 + r) * C + j0 + jt * 16 + col],
                      acc[jt][r]);
}

__global__ __launch_bounds__(256) void out_kernel(const float* __restrict__ g,
                                                  const float* __restrict__ lin_w,
                                                  const float* __restrict__ lin_b,
                                                  float* __restrict__ out) {
    __shared__ float gs[C];
    int i = blockIdx.x, j = threadIdx.x;
    gs[j] = g[(size_t)i * C + j];
    __syncthreads();
    float acc = lin_b[j];
    const float* wrow = lin_w + (size_t)j * C;
    for (int k = 0; k < C; k++) acc += gs[k] * wrow[k];
    out[(size_t)i * C + j] = (acc > 0.f) ? acc : SLOPE * acc;
}

extern "C" void kernel_launch(void* const* d_in, const int* in_sizes, int n_in,
                              void* d_out, int out_size, void* d_ws, size_t ws_size,
                              hipStream_t stream) {
    const float* emb    = (const float*)d_in[0];
    const float* conv_w = (const float*)d_in[1];
    const float* conv_b = (const float*)d_in[2];
    const float* lin_w  = (const float*)d_in[3];
    const float* lin_b  = (const float*)d_in[4];
    const int*   eidx   = (const int*)d_in[5];
    const int* node_idx = eidx;        // edge_index[0]
    const int* edge_idx = eidx + NNZ;  // edge_index[1]

    char* ws = (char*)d_ws;
    int* cnt_n = (int*)(ws + OFF_CNT_N);
    int* cnt_e = (int*)(ws + OFF_CNT_E);
    int* cur_e = (int*)(ws + OFF_CBKT_E);
    int* cur_n = (int*)(ws + OFF_CBKT_N);
    float* g   = (float*)(ws + OFF_G);
    int* rs_n  = (int*)(ws + OFF_RS_N);
    int* rs_e  = (int*)(ws + OFF_RS_E);
    int* bsum_n = (int*)(ws + OFF_BSUM_N);
    int* bsum_e = (int*)(ws + OFF_BSUM_E);
    int* buf_e = (int*)(ws + OFF_BUF_E);
    int* buf_n = (int*)(ws + OFF_BUF_N);
    int* csr_e = (int*)(ws + OFF_CSR_E);
    int* csr_n = (int*)(ws + OFF_CSR_N);
    uint4* embh4 = (uint4*)(ws + OFF_EMBH);
    float* e_acc = (float*)(ws + OFF_EACC);
    unsigned short* e2h = (unsigned short*)(ws + OFF_E2);
    unsigned short* yT  = (unsigned short*)(ws + OFF_YT);
    float* out = (float*)d_out;

    int n4 = ZERO_BYTES / 16;
    zero_kernel<<<(n4 + 255) / 256, 256, 0, stream>>>((float4*)ws, n4);

    cast_emb_kernel<<<6250, 256, 0, stream>>>((const float4*)emb, embh4);

    hist_kernel<<<(NNZ + 255) / 256, 256, 0, stream>>>(node_idx, edge_idx, cnt_n, cnt_e);

    scan_block_kernel<<<(N_NODES + 255) / 256, 256, 0, stream>>>(cnt_n, N_NODES, rs_n, bsum_n);
    scan_block_kernel<<<(N_EDGES + 255) / 256, 256, 0, stream>>>(cnt_e, N_EDGES, rs_e, bsum_e);
    scan_sums_kernel<<<1, 256, 0, stream>>>(bsum_n, (N_NODES + 255) / 256);
    scan_sums_kernel<<<1, 256, 0, stream>>>(bsum_e, (N_EDGES + 255) / 256);
    scan_fix_kernel<<<(N_NODES + 255) / 256, 256, 0, stream>>>(rs_n, N_NODES, bsum_n);
    scan_fix_kernel<<<(N_EDGES + 255) / 256, 256, 0, stream>>>(rs_e, N_EDGES, bsum_e);

    bucket_scatter_kernel<<<256, 256, 0, stream>>>(node_idx, edge_idx, rs_e, rs_n,
                                                   cur_e, cur_n, buf_e, buf_n);

    bucket_sort_kernel<<<2 * NB, 256, 0, stream>>>(buf_e, buf_n, rs_e, rs_n, csr_e, csr_n);

    edge_aggregate_kernel<<<(N_EDGES + 3) / 4, 256, 0, stream>>>(embh4, csr_e, rs_e, e_acc);

    edge_gemm_kernel<<<dim3((N_EDGES + 63) / 64, C / 64), 256, 0, stream>>>(e_acc, rs_e, conv_w, e2h);

    node_aggregate_t_kernel<<<KTOT / 32, 256, 0, stream>>>((const uint4*)e2h, csr_n, rs_n,
                                                           conv_b, yT);

    gram_mfma_kernel<<<dim3(4, 4, NZB), 256, 0, stream>>>(yT, g);

    out_kernel<<<C, 256, 0, stream>>>(g, lin_w, lin_b, out);
}

// Round 7
// 325.778 us; speedup vs baseline: 17.5651x; 1.2942x over previous
//
#include <hip/hip_runtime.h>

#define N_NODES 50000
#define N_EDGES 10000
#define NNZ     800000
#define C       256
#define SLOPE   0.01f
#define KTOT    50048   // node count padded to multiple of 64
#define KCHUNK  1088    // 17 * 64
#define NZB     46      // KTOT / KCHUNK

#define NB      250     // coarse buckets per side
#define EB_E    40      // edges per bucket   (250*40  = 10000)
#define EB_N    200     // nodes per bucket   (250*200 = 50000)
#define CHUNK   3125    // NNZ / 256 blocks
#define CAP     6000    // LDS item capacity in bucket_sort (mean 3200, sd ~57)

// ---- workspace layout (bytes) ----
#define OFF_CC_E    0          // 250*4 coarse counts (edge)
#define OFF_CC_N    1024       // 250*4 coarse counts (node)
#define OFF_CUR_E   2048       // 250*4 scatter cursors
#define OFF_CUR_N   3072       // 250*4
#define OFF_G       4096       // 256*256*4
#define ZERO_BYTES  266240     // zero region [0, ZERO_BYTES), /16 ok
#define OFF_CB_E    266240     // 251*4 coarse bases (edge)
#define OFF_CB_N    267264     // 251*4 coarse bases (node)
#define OFF_RS_N    268288     // 50001*4 (written by bucket_sort)
#define OFF_RS_E    468480     // 10001*4 (written by bucket_sort)
#define OFF_BUF_E   508672     // 800000*4 bucketed items (edge side)
#define OFF_BUF_N   3708672    // 800000*4 bucketed items (node side)
#define OFF_CSR_E   6908672    // 800000*4 node ids grouped by edge
#define OFF_CSR_N   10108672   // 800000*4 edge ids grouped by node
#define OFF_EMBH    13308672   // 50000*256*2 bf16 (dead after edge_aggregate)
#define OFF_YT      13308672   // 256*50048*2 bf16 — ALIASES embh (embh dead first)
#define OFF_EACC    38933248   // 10000*256*4 f32
#define OFF_E2      49173248   // 10000*256*2 bf16 -> end 54,293,248

typedef __attribute__((ext_vector_type(8))) short short8;
typedef __attribute__((ext_vector_type(4))) float floatx4;

static __device__ __forceinline__ unsigned short f2bf(float f) {
    unsigned int u = __float_as_uint(f);
    u = (u + 0x7fffu + ((u >> 16) & 1u)) >> 16;   // RNE
    return (unsigned short)u;
}

// unpack uint4 (8 bf16) and accumulate into a[0..7]
static __device__ __forceinline__ void acc_bf8(const uint4 d, float* a) {
    a[0] += __uint_as_float(d.x << 16);
    a[1] += __uint_as_float(d.x & 0xffff0000u);
    a[2] += __uint_as_float(d.y << 16);
    a[3] += __uint_as_float(d.y & 0xffff0000u);
    a[4] += __uint_as_float(d.z << 16);
    a[5] += __uint_as_float(d.z & 0xffff0000u);
    a[6] += __uint_as_float(d.w << 16);
    a[7] += __uint_as_float(d.w & 0xffff0000u);
}

// this half-wave accumulates rows csr[s+half], csr[s+half+2], ... < t.
// Index loads are same-address broadcast loads (safe under divergence,
// unlike __shfl whose inactive source lanes return undefined).
static __device__ __forceinline__ void gather_rows(const uint4* __restrict__ tbl4,
                                                   const int* __restrict__ csr,
                                                   int s, int t, int half, int l32,
                                                   float* a) {
    int i = s + half;
    for (; i + 6 < t; i += 8) {
        int e0 = csr[i];
        int e1 = csr[i + 2];
        int e2 = csr[i + 4];
        int e3 = csr[i + 6];
        uint4 d0 = tbl4[(size_t)e0 * 32 + l32];
        uint4 d1 = tbl4[(size_t)e1 * 32 + l32];
        uint4 d2 = tbl4[(size_t)e2 * 32 + l32];
        uint4 d3 = tbl4[(size_t)e3 * 32 + l32];
        acc_bf8(d0, a); acc_bf8(d1, a); acc_bf8(d2, a); acc_bf8(d3, a);
    }
    for (; i < t; i += 2) {
        uint4 d = tbl4[(size_t)csr[i] * 32 + l32];
        acc_bf8(d, a);
    }
}

__global__ __launch_bounds__(256) void zero_kernel(float4* __restrict__ p, int n4) {
    int i = blockIdx.x * 256 + threadIdx.x;
    if (i < n4) p[i] = make_float4(0.f, 0.f, 0.f, 0.f);
}

// emb f32 -> bf16 (8 elems/thread)
__global__ __launch_bounds__(256) void cast_emb_kernel(const float4* __restrict__ emb4,
                                                       uint4* __restrict__ embh4) {
    int i = blockIdx.x * 256 + threadIdx.x;   // 1.6M threads
    float4 f0 = emb4[2 * i], f1 = emb4[2 * i + 1];
    uint4 o;
    o.x = f2bf(f0.x) | ((unsigned)f2bf(f0.y) << 16);
    o.y = f2bf(f0.z) | ((unsigned)f2bf(f0.w) << 16);
    o.z = f2bf(f1.x) | ((unsigned)f2bf(f1.y) << 16);
    o.w = f2bf(f1.z) | ((unsigned)f2bf(f1.w) << 16);
    embh4[i] = o;
}

// coarse histogram: per-block LDS hist over 250 buckets/side, then one global
// atomic per (block,bucket) — 128k cold atomics vs 1.6M hot (old hist_kernel)
__global__ __launch_bounds__(256) void coarse_count_kernel(const int* __restrict__ node_idx,
                                                           const int* __restrict__ edge_idx,
                                                           int* __restrict__ cc_e,
                                                           int* __restrict__ cc_n) {
    __shared__ int he[NB], hn[NB];
    int tid = threadIdx.x;
    int base = blockIdx.x * CHUNK;
    for (int i = tid; i < NB; i += 256) { he[i] = 0; hn[i] = 0; }
    __syncthreads();
    for (int i = tid; i < CHUNK; i += 256) {
        atomicAdd(&he[edge_idx[base + i] / EB_E], 1);
        atomicAdd(&hn[node_idx[base + i] / EB_N], 1);
    }
    __syncthreads();
    for (int k = tid; k < NB; k += 256) {
        if (he[k]) atomicAdd(&cc_e[k], he[k]);
        if (hn[k]) atomicAdd(&cc_n[k], hn[k]);
    }
}

// single-block exclusive scan of both coarse-count arrays -> coarse bases
__global__ __launch_bounds__(256) void coarse_scan_kernel(const int* __restrict__ cc_e,
                                                          const int* __restrict__ cc_n,
                                                          int* __restrict__ cb_e,
                                                          int* __restrict__ cb_n) {
    __shared__ int tmp[256];
    int tid = threadIdx.x;
    // edge side
    int v = (tid < NB) ? cc_e[tid] : 0;
    tmp[tid] = v;
    __syncthreads();
    for (int off = 1; off < 256; off <<= 1) {
        int t = (tid >= off) ? tmp[tid - off] : 0;
        __syncthreads();
        tmp[tid] += t;
        __syncthreads();
    }
    if (tid < NB) cb_e[tid + 1] = tmp[tid];
    if (tid == 0) cb_e[0] = 0;
    __syncthreads();
    // node side
    v = (tid < NB) ? cc_n[tid] : 0;
    tmp[tid] = v;
    __syncthreads();
    for (int off = 1; off < 256; off <<= 1) {
        int t = (tid >= off) ? tmp[tid - off] : 0;
        __syncthreads();
        tmp[tid] += t;
        __syncthreads();
    }
    if (tid < NB) cb_n[tid + 1] = tmp[tid];
    if (tid == 0) cb_n[0] = 0;
}

// pass 1: scatter incidences into coarse buckets (both sides), line-dense writes
__global__ __launch_bounds__(256) void bucket_scatter_kernel(const int* __restrict__ node_idx,
                                                             const int* __restrict__ edge_idx,
                                                             const int* __restrict__ cb_e,
                                                             const int* __restrict__ cb_n,
                                                             int* __restrict__ cur_e,
                                                             int* __restrict__ cur_n,
                                                             int* __restrict__ buf_e,
                                                             int* __restrict__ buf_n) {
    __shared__ int he[NB], hn[NB], be[NB], bn[NB];
    int tid = threadIdx.x;
    int base = blockIdx.x * CHUNK;
    for (int i = tid; i < NB; i += 256) { he[i] = 0; hn[i] = 0; }
    __syncthreads();
    for (int i = tid; i < CHUNK; i += 256) {
        int e = edge_idx[base + i], v = node_idx[base + i];
        atomicAdd(&he[e / EB_E], 1);
        atomicAdd(&hn[v / EB_N], 1);
    }
    __syncthreads();
    for (int k = tid; k < NB; k += 256) {
        int c = he[k];
        be[k] = cb_e[k] + (c ? atomicAdd(&cur_e[k], c) : 0);
        int cn = hn[k];
        bn[k] = cb_n[k] + (cn ? atomicAdd(&cur_n[k], cn) : 0);
    }
    __syncthreads();
    for (int i = tid; i < NB; i += 256) { he[i] = 0; hn[i] = 0; }
    __syncthreads();
    for (int i = tid; i < CHUNK; i += 256) {
        int e = edge_idx[base + i], v = node_idx[base + i];
        int ke = e / EB_E, kn = v / EB_N;
        int oe = atomicAdd(&he[ke], 1);
        buf_e[be[ke] + oe] = (v << 6) | (e - ke * EB_E);
        int on = atomicAdd(&hn[kn], 1);
        buf_n[bn[kn] + on] = (e << 8) | (v - kn * EB_N);
    }
}

// pass 2: per-bucket LDS counting sort -> final CSR + emit fine rs from the
// bucket-local histogram (replaces the old global hist + 3-kernel scan)
__global__ __launch_bounds__(256) void bucket_sort_kernel(const int* __restrict__ buf_e,
                                                          const int* __restrict__ buf_n,
                                                          const int* __restrict__ cb_e,
                                                          const int* __restrict__ cb_n,
                                                          int* __restrict__ csr_e,
                                                          int* __restrict__ csr_n,
                                                          int* __restrict__ rs_e,
                                                          int* __restrict__ rs_n) {
    __shared__ int A[CAP];
    __shared__ int h[EB_N], bs[EB_N];
    int tid = threadIdx.x;
    bool edgeSide = blockIdx.x < NB;
    int k = edgeSide ? blockIdx.x : blockIdx.x - NB;
    int eb = edgeSide ? EB_E : EB_N;
    int shift = edgeSide ? 6 : 8;
    int mask = (1 << shift) - 1;
    const int* cb  = edgeSide ? cb_e : cb_n;
    const int* buf = edgeSide ? buf_e : buf_n;
    int* csr       = edgeSide ? csr_e : csr_n;
    int* rs        = edgeSide ? rs_e : rs_n;
    int base = cb[k];
    int cnt = cb[k + 1] - base;
    for (int i = tid; i < eb; i += 256) h[i] = 0;
    __syncthreads();
    for (int i = tid; i < cnt; i += 256) {
        int it = buf[base + i];
        if (i < CAP) A[i] = it;
        atomicAdd(&h[it & mask], 1);
    }
    __syncthreads();
    if (tid == 0) {
        int s = 0;
        for (int j = 0; j < eb; j++) { bs[j] = s; s += h[j]; }
    }
    __syncthreads();
    // emit fine rs for this bucket's ids + reset h for placement pass
    for (int j = tid; j < eb; j += 256) {
        rs[k * eb + j] = base + bs[j];
        h[j] = 0;
    }
    if (tid == 0 && k == NB - 1) rs[edgeSide ? N_EDGES : N_NODES] = NNZ;
    __syncthreads();
    for (int i = tid; i < cnt; i += 256) {
        int it = (i < CAP) ? A[i] : buf[base + i];
        int loc = it & mask;
        int off = bs[loc] + atomicAdd(&h[loc], 1);
        csr[base + off] = it >> shift;
    }
}

// one wave per hyperedge; 4-deep pipelined gathers (broadcast index loads)
__global__ __launch_bounds__(256) void edge_aggregate_kernel(const uint4* __restrict__ embh4,
                                                             const int* __restrict__ csr_e,
                                                             const int* __restrict__ rs_e,
                                                             float* __restrict__ e_acc) {
    int e = blockIdx.x * 4 + (threadIdx.x >> 6);
    if (e >= N_EDGES) return;
    int lane = threadIdx.x & 63;
    int half = lane >> 5, l32 = lane & 31;
    int s = rs_e[e], t = rs_e[e + 1];
    float a[8] = {0.f, 0.f, 0.f, 0.f, 0.f, 0.f, 0.f, 0.f};
    gather_rows(embh4, csr_e, s, t, half, l32, a);
    #pragma unroll
    for (int j = 0; j < 8; j++) a[j] += __shfl_xor(a[j], 32);
    if (half == 0) {
        float* dst = e_acc + (size_t)e * C + l32 * 8;
        ((float4*)dst)[0] = make_float4(a[0], a[1], a[2], a[3]);
        ((float4*)dst)[1] = make_float4(a[4], a[5], a[6], a[7]);
    }
}

// e2[m][n] = Binv[m] * sum_k e_acc[m][k] * conv_w[n][k], bf16 out
__global__ __launch_bounds__(256) void edge_gemm_kernel(const float* __restrict__ e_acc,
                                                        const int* __restrict__ rs_e,
                                                        const float* __restrict__ conv_w,
                                                        unsigned short* __restrict__ e2h) {
    __shared__ float As[16][65];
    __shared__ float Bs[16][65];
    int m0 = blockIdx.x * 64, n0 = blockIdx.y * 64;
    int tx = threadIdx.x & 15, ty = threadIdx.x >> 4;
    float acc[4][4] = {};
    for (int kb = 0; kb < C; kb += 16) {
        #pragma unroll
        for (int i = 0; i < 4; i++) {
            int idx = threadIdx.x + i * 256;
            int kk = idx & 15, mm = idx >> 4;
            int m = m0 + mm;
            As[kk][mm] = (m < N_EDGES) ? e_acc[(size_t)m * C + kb + kk] : 0.0f;
            Bs[kk][mm] = conv_w[(size_t)(n0 + mm) * C + kb + kk];
        }
        __syncthreads();
        #pragma unroll
        for (int k = 0; k < 16; k++) {
            float a[4], b[4];
            #pragma unroll
            for (int r = 0; r < 4; r++) a[r] = As[k][ty * 4 + r];
            #pragma unroll
            for (int c = 0; c < 4; c++) b[c] = Bs[k][tx * 4 + c];
            #pragma unroll
            for (int r = 0; r < 4; r++)
                #pragma unroll
                for (int c = 0; c < 4; c++) acc[r][c] += a[r] * b[c];
        }
        __syncthreads();
    }
    #pragma unroll
    for (int r = 0; r < 4; r++) {
        int m = m0 + ty * 4 + r;
        if (m < N_EDGES) {
            int deg = rs_e[m + 1] - rs_e[m];
            float binv = (deg > 0) ? 1.0f / (float)deg : 0.0f;
            ushort4 o;
            o.x = f2bf(acc[r][0] * binv);
            o.y = f2bf(acc[r][1] * binv);
            o.z = f2bf(acc[r][2] * binv);
            o.w = f2bf(acc[r][3] * binv);
            *(ushort4*)(e2h + (size_t)m * C + n0 + tx * 4) = o;
        }
    }
}

// 32 nodes per block (4 waves x 8 nodes); pipelined gathers; fused
// Dinv/bias/lrelu; write yT (transposed via LDS)
__global__ __launch_bounds__(256) void node_aggregate_t_kernel(const uint4* __restrict__ e2h4,
                                                               const int* __restrict__ csr_n,
                                                               const int* __restrict__ rs_n,
                                                               const float* __restrict__ conv_b,
                                                               unsigned short* __restrict__ yT) {
    __shared__ __align__(16) unsigned short T[32][256];  // [node][ch]
    int n0 = blockIdx.x * 32;
    int tid = threadIdx.x;
    int w = tid >> 6, lane = tid & 63;
    int half = lane >> 5, l32 = lane & 31;
    int base = n0 + w * 8;
    // prefetch rs for this wave's 8 nodes; __shfl below runs with ALL 64 lanes
    // active (uniform q loop) so inactive-source-lane hazard does not apply
    int rsv = rs_n[min(base + lane, N_NODES)];
    float4 b0 = ((const float4*)conv_b)[l32 * 2];
    float4 b1 = ((const float4*)conv_b)[l32 * 2 + 1];
    float bb[8] = {b0.x, b0.y, b0.z, b0.w, b1.x, b1.y, b1.z, b1.w};
    for (int q = 0; q < 8; q++) {
        int v = base + q;
        int s = __shfl(rsv, q), t = __shfl(rsv, q + 1);
        float a[8] = {0.f, 0.f, 0.f, 0.f, 0.f, 0.f, 0.f, 0.f};
        gather_rows(e2h4, csr_n, s, t, half, l32, a);
        #pragma unroll
        for (int j = 0; j < 8; j++) a[j] += __shfl_xor(a[j], 32);
        float dinv = (t > s) ? 1.0f / (float)(t - s) : 0.0f;
        unsigned int pk[4];
        #pragma unroll
        for (int j = 0; j < 4; j++) {
            float r0 = a[2 * j] * dinv + bb[2 * j];
            float r1 = a[2 * j + 1] * dinv + bb[2 * j + 1];
            r0 = (r0 > 0.f) ? r0 : SLOPE * r0;
            r1 = (r1 > 0.f) ? r1 : SLOPE * r1;
            if (v >= N_NODES) { r0 = 0.f; r1 = 0.f; }   // zero-pad rows
            pk[j] = f2bf(r0) | ((unsigned)f2bf(r1) << 16);
        }
        if (half == 0) {
            uint4 o; o.x = pk[0]; o.y = pk[1]; o.z = pk[2]; o.w = pk[3];
            *(uint4*)(&T[w * 8 + q][l32 * 8]) = o;
        }
    }
    __syncthreads();
    int ch = tid;
    #pragma unroll
    for (int jj = 0; jj < 4; jj++) {
        uint4 o;
        o.x = T[jj * 8 + 0][ch] | ((unsigned)T[jj * 8 + 1][ch] << 16);
        o.y = T[jj * 8 + 2][ch] | ((unsigned)T[jj * 8 + 3][ch] << 16);
        o.z = T[jj * 8 + 4][ch] | ((unsigned)T[jj * 8 + 5][ch] << 16);
        o.w = T[jj * 8 + 6][ch] | ((unsigned)T[jj * 8 + 7][ch] << 16);
        *(uint4*)(yT + (size_t)ch * KTOT + n0 + jj * 8) = o;
    }
}

// g += yT-tile^T yT-tile via mfma_f32_16x16x32_bf16; grid (4,4,NZB)
__global__ __launch_bounds__(256) void gram_mfma_kernel(const unsigned short* __restrict__ yT,
                                                        float* __restrict__ g) {
    __shared__ __align__(16) unsigned short As[64 * 72];  // [col][k], stride 72
    __shared__ __align__(16) unsigned short Bs[64 * 72];
    int i0 = blockIdx.x * 64, j0 = blockIdx.y * 64;
    int kb0 = blockIdx.z * KCHUNK;
    int tid = threadIdx.x;
    int w = tid >> 6, lane = tid & 63;
    int col = lane & 15, quad = lane >> 4;
    floatx4 acc[4] = {};
    for (int step = 0; step < 17; step++) {
        int kb = kb0 + step * 64;
        __syncthreads();
        #pragma unroll
        for (int l = 0; l < 2; l++) {
            int slot = tid + l * 256;          // 0..511
            int row = slot >> 3, grp = slot & 7;
            uint4 da = *(const uint4*)(yT + (size_t)(i0 + row) * KTOT + kb + grp * 8);
            *(uint4*)(&As[row * 72 + grp * 8]) = da;
            uint4 db = *(const uint4*)(yT + (size_t)(j0 + row) * KTOT + kb + grp * 8);
            *(uint4*)(&Bs[row * 72 + grp * 8]) = db;
        }
        __syncthreads();
        #pragma unroll
        for (int sub = 0; sub < 2; sub++) {
            short8 a = *(const short8*)(&As[(w * 16 + col) * 72 + sub * 32 + quad * 8]);
            #pragma unroll
            for (int jt = 0; jt < 4; jt++) {
                short8 b = *(const short8*)(&Bs[(jt * 16 + col) * 72 + sub * 32 + quad * 8]);
                acc[jt] = __builtin_amdgcn_mfma_f32_16x16x32_bf16(a, b, acc[jt], 0, 0, 0);
            }
        }
    }
    #pragma unroll
    for (int jt = 0; jt < 4; jt++)
        #pragma unroll
        for (int r = 0; r < 4; r++)
            atomicAdd(&g[(size_t)(i0 + w * 16 + quad * 4 + r) * C + j0 + jt * 16 + col],
                      acc[jt][r]);
}

__global__ __launch_bounds__(256) void out_kernel(const float* __restrict__ g,
                                                  const float* __restrict__ lin_w,
                                                  const float* __restrict__ lin_b,
                                                  float* __restrict__ out) {
    __shared__ float gs[C];
    int i = blockIdx.x, j = threadIdx.x;
    gs[j] = g[(size_t)i * C + j];
    __syncthreads();
    float acc = lin_b[j];
    const float* wrow = lin_w + (size_t)j * C;
    for (int k = 0; k < C; k++) acc += gs[k] * wrow[k];
    out[(size_t)i * C + j] = (acc > 0.f) ? acc : SLOPE * acc;
}

extern "C" void kernel_launch(void* const* d_in, const int* in_sizes, int n_in,
                              void* d_out, int out_size, void* d_ws, size_t ws_size,
                              hipStream_t stream) {
    const float* emb    = (const float*)d_in[0];
    const float* conv_w = (const float*)d_in[1];
    const float* conv_b = (const float*)d_in[2];
    const float* lin_w  = (const float*)d_in[3];
    const float* lin_b  = (const float*)d_in[4];
    const int*   eidx   = (const int*)d_in[5];
    const int* node_idx = eidx;        // edge_index[0]
    const int* edge_idx = eidx + NNZ;  // edge_index[1]

    char* ws = (char*)d_ws;
    int* cc_e  = (int*)(ws + OFF_CC_E);
    int* cc_n  = (int*)(ws + OFF_CC_N);
    int* cur_e = (int*)(ws + OFF_CUR_E);
    int* cur_n = (int*)(ws + OFF_CUR_N);
    float* g   = (float*)(ws + OFF_G);
    int* cb_e  = (int*)(ws + OFF_CB_E);
    int* cb_n  = (int*)(ws + OFF_CB_N);
    int* rs_n  = (int*)(ws + OFF_RS_N);
    int* rs_e  = (int*)(ws + OFF_RS_E);
    int* buf_e = (int*)(ws + OFF_BUF_E);
    int* buf_n = (int*)(ws + OFF_BUF_N);
    int* csr_e = (int*)(ws + OFF_CSR_E);
    int* csr_n = (int*)(ws + OFF_CSR_N);
    uint4* embh4 = (uint4*)(ws + OFF_EMBH);
    float* e_acc = (float*)(ws + OFF_EACC);
    unsigned short* e2h = (unsigned short*)(ws + OFF_E2);
    unsigned short* yT  = (unsigned short*)(ws + OFF_YT);
    float* out = (float*)d_out;

    int n4 = ZERO_BYTES / 16;
    zero_kernel<<<(n4 + 255) / 256, 256, 0, stream>>>((float4*)ws, n4);

    cast_emb_kernel<<<6250, 256, 0, stream>>>((const float4*)emb, embh4);

    coarse_count_kernel<<<256, 256, 0, stream>>>(node_idx, edge_idx, cc_e, cc_n);

    coarse_scan_kernel<<<1, 256, 0, stream>>>(cc_e, cc_n, cb_e, cb_n);

    bucket_scatter_kernel<<<256, 256, 0, stream>>>(node_idx, edge_idx, cb_e, cb_n,
                                                   cur_e, cur_n, buf_e, buf_n);

    bucket_sort_kernel<<<2 * NB, 256, 0, stream>>>(buf_e, buf_n, cb_e, cb_n,
                                                   csr_e, csr_n, rs_e, rs_n);

    edge_aggregate_kernel<<<(N_EDGES + 3) / 4, 256, 0, stream>>>(embh4, csr_e, rs_e, e_acc);

    edge_gemm_kernel<<<dim3((N_EDGES + 63) / 64, C / 64), 256, 0, stream>>>(e_acc, rs_e, conv_w, e2h);

    node_aggregate_t_kernel<<<KTOT / 32, 256, 0, stream>>>((const uint4*)e2h, csr_n, rs_n,
                                                           conv_b, yT);

    gram_mfma_kernel<<<dim3(4, 4, NZB), 256, 0, stream>>>(yT, g);

    out_kernel<<<C, 256, 0, stream>>>(g, lin_w, lin_b, out);
}